// Round 5
// baseline (477.579 us; speedup 1.0000x reference)
//
#include <hip/hip_runtime.h>
#include <cstddef>

#define NN   30000
#define NNP  30016          /* NN ints rounded to 256B alloc granularity */
#define NE   240000
#define D1   512
#define D2   128
#define NCLS 20
#define CAP  64             /* padded-CSR slots per node; Poisson(8) tail @64 ~ 1e-38 */
#define NPB  16             /* nodes (=waves) per gat block; NN % NPB == 0 */
#define CAST_TOT 1025536          /* x(960000) + 4 weights(16384 ea), float4 units */
#define IDG_TOT  (CAST_TOT + NE)  /* + one thread per edge for CSR-build atomics */

typedef __attribute__((ext_vector_type(8))) short short8;
typedef __attribute__((ext_vector_type(4))) float f32x4;
typedef __attribute__((ext_vector_type(2))) float f32x2;

__device__ __forceinline__ unsigned short f2b(float f) {
  union { float f; unsigned int u; } c; c.f = f;
  unsigned int r = (c.u + 0x7fff + ((c.u >> 16) & 1)) >> 16;  // RNE
  return (unsigned short)r;
}
__device__ __forceinline__ float b2f(unsigned short u) {
  union { unsigned int u; float f; } c; c.u = (unsigned int)u << 16;
  return c.f;
}
// two packed bf16 (little-endian: low half = even channel) -> f32x2
__device__ __forceinline__ f32x2 bpair(unsigned int t) {
  f32x2 r;
  r.x = __uint_as_float(t << 16);
  r.y = __uint_as_float(t & 0xffff0000u);
  return r;
}

// ---------------------------------------------------------------- cast + padded-CSR build
// Single kernel replaces initdeg+scan+fill. Edges land directly in
// se_pad[d*CAP + atomicAdd(cnti[d])]; within-node order is atomic-
// nondeterministic — same class as the old cursor-atomic fill (absmax stable
// across 5 rounds). lsum accumulated here; la computed in gat prologue.
__global__ __launch_bounds__(256) void k_build(
    const float* __restrict__ x,
    const float* __restrict__ Wl1, const float* __restrict__ Wr1,
    const float* __restrict__ Wl2, const float* __restrict__ Wr2,
    const int* __restrict__ src, const int* __restrict__ dst,
    const float* __restrict__ eattr,
    int* __restrict__ cnti, float* __restrict__ lsum,
    int2* __restrict__ se,
    unsigned short* __restrict__ xb,
    unsigned short* __restrict__ Wc1, unsigned short* __restrict__ Wc2) {
  int i = blockIdx.x * 256 + threadIdx.x;
  if (i >= IDG_TOT) return;
  if (i >= CAST_TOT) {                 // CSR build + loop-attr atomics
    int e = i - CAST_TOT;
    int d = dst[e];
    int pos = atomicAdd(&cnti[d], 1);
    if (pos < CAP) se[(size_t)d * CAP + pos] = make_int2(src[e], __float_as_int(eattr[e]));
    atomicAdd(&lsum[d], eattr[e]);
    return;
  }
  const float* in; unsigned short* outp; int off;
  if      (i <  960000) { in = x;   outp = xb;          off = i; }
  else if (i <  976384) { in = Wl1; outp = Wc1;         off = i -  960000; }
  else if (i <  992768) { in = Wr1; outp = Wc1 + 65536; off = i -  976384; }
  else if (i < 1009152) { in = Wl2; outp = Wc2;         off = i -  992768; }
  else                  { in = Wr2; outp = Wc2 + 65536; off = i - 1009152; }
  float4 v = ((const float4*)in)[off];
  ushort4 o;
  o.x = f2b(v.x); o.y = f2b(v.y); o.z = f2b(v.z); o.w = f2b(v.w);
  ((ushort4*)outp)[off] = o;
}

// ---------------------------------------------------------------- bf16 MFMA GEMM
// [Cl|Cr][m,n] = sum_k A[m,k]*W[n,k] + bias, W = [Wl;Wr] concat in n; split out.
// m97-style staging: UNPADDED LDS, global_load_lds width=16 — wave covers
// 512/BK rows per issue; dest is wave-uniform base + lane*16 (lane-contiguous).
// BK is a template param: gemm1 (K=128, 1880 blocks) keeps BK=64 (32 KB LDS,
// ~5 wg/CU residency); gemm2 (K=512, 470 blocks <2/CU anyway) uses BK=128 to
// halve barrier-drain rounds (m132's occupancy penalty cannot bind there).
// No OOB row guard: reads past M land in later workspace buffers (no fault);
// garbage only contaminates rows >= M, which the epilogue store masks.
template <int BN, int NT, int BK>   // NT = BN/32 n-tiles per wave
__global__ __launch_bounds__(256) void gemm_mfma(
    const unsigned short* __restrict__ A, const unsigned short* __restrict__ W,
    const float* __restrict__ bl, const float* __restrict__ br, int Nhalf,
    unsigned short* __restrict__ Cl, unsigned short* __restrict__ Cr,
    int M, int N, int K) {
  constexpr int BM = 128, LDK = BK;    // unpadded (global_load_lds)
  constexpr int RPI = 512 / BK;        // rows per wave per load issue (8@64, 4@128)
  constexpr int LPR = BK / 8;          // lanes per row (8@64, 16@128)
  __shared__ __align__(16) unsigned short As[BM * LDK];
  __shared__ __align__(16) unsigned short Bs[BN * LDK];
  const int bm = blockIdx.y * BM;
  const int bn = blockIdx.x * BN;
  const int tid = threadIdx.x;
  const int lane = tid & 63;
  const int wid = __builtin_amdgcn_readfirstlane(tid >> 6);  // wave-uniform (SGPR)
  const int wm = (wid >> 1) * 64;
  const int wn = (wid & 1) * (NT * 16);
  const int l16 = lane & 15, lq = lane >> 4;
  const int lrow = lane / LPR;         // staging: row within RPI
  const int lcol = (lane % LPR) * 8;   // staging: k-offset (8 bf16 = 16 B)

  f32x4 acc[4][NT];
#pragma unroll
  for (int i = 0; i < 4; ++i)
#pragma unroll
    for (int j = 0; j < NT; ++j) acc[i][j] = (f32x4){0.f, 0.f, 0.f, 0.f};

  for (int k0 = 0; k0 < K; k0 += BK) {
#pragma unroll
    for (int p = 0; p < BM / (4 * RPI); ++p) {
      int r = p * (4 * RPI) + wid * RPI;
      const unsigned short* gp = A + (size_t)(bm + r + lrow) * K + k0 + lcol;
      __builtin_amdgcn_global_load_lds(
          (const __attribute__((address_space(1))) unsigned int*)gp,
          (__attribute__((address_space(3))) unsigned int*)(As + (size_t)r * LDK),
          16, 0, 0);
    }
#pragma unroll
    for (int p = 0; p < BN / (4 * RPI); ++p) {
      int r = p * (4 * RPI) + wid * RPI;
      const unsigned short* gp = W + (size_t)(bn + r + lrow) * K + k0 + lcol;
      __builtin_amdgcn_global_load_lds(
          (const __attribute__((address_space(1))) unsigned int*)gp,
          (__attribute__((address_space(3))) unsigned int*)(Bs + (size_t)r * LDK),
          16, 0, 0);
    }
    __syncthreads();
#pragma unroll
    for (int kh = 0; kh < BK / 32; ++kh) {
      short8 af[4], bfr[NT];
#pragma unroll
      for (int mt = 0; mt < 4; ++mt)
        af[mt] = *(const short8*)&As[(wm + mt * 16 + l16) * LDK + kh * 32 + lq * 8];
#pragma unroll
      for (int nt = 0; nt < NT; ++nt)
        bfr[nt] = *(const short8*)&Bs[(wn + nt * 16 + l16) * LDK + kh * 32 + lq * 8];
#pragma unroll
      for (int mt = 0; mt < 4; ++mt)
#pragma unroll
        for (int nt = 0; nt < NT; ++nt)
          acc[mt][nt] = __builtin_amdgcn_mfma_f32_16x16x32_bf16(
              af[mt], bfr[nt], acc[mt][nt], 0, 0, 0);
    }
    __syncthreads();
  }

#pragma unroll
  for (int mt = 0; mt < 4; ++mt)
#pragma unroll
    for (int nt = 0; nt < NT; ++nt) {
      int col = bn + wn + nt * 16 + l16;
      bool left = col < Nhalf;                 // uniform: 64-col strips
      int cc = left ? col : col - Nhalf;
      float b = left ? bl[cc] : br[cc];
      unsigned short* Cp = left ? Cl : Cr;
#pragma unroll
      for (int r = 0; r < 4; ++r) {
        int row = bm + wm + mt * 16 + lq * 4 + r;
        if (row < M) Cp[(size_t)row * Nhalf + cc] = f2b(acc[mt][nt][r] + b);
      }
    }
}

// ---------------------------------------------------------------- fused GATv2 aggregate
// ONE wave per destination node, both heads (lanes [0,32)=h0, [32,64)=h1).
// Per-edge logit: 5-stage half-wave butterfly serves both heads at once.
// 4 edges/iteration; packed f32x2 VOP3P math; wgt-mask only in tail chunk.
// R5: NPB=16 nodes per block (1024 threads). Rationale: with 4-wave blocks the
// CP dispatch rate (~117 wg/us observed) capped residency at ~10 waves/CU
// (occupancy 31%, Little's law closes exactly); 16-wave blocks cut the wg
// count 7500->1875 so residency is slot-limited (2 wg/CU = 32 waves) instead.
// __launch_bounds__(1024,8) pins VGPR <= 64 (R1: >64 halves the wave cap).
template <int D, bool DO_SILU, bool OBF, bool HEAD_GEMM>
__global__ __launch_bounds__(1024, 8) void k_gat_node(
    const int2* __restrict__ se,
    const int* __restrict__ cnti, const float* __restrict__ lsum,
    const unsigned short* __restrict__ xl, const unsigned short* __restrict__ xr,
    const float* __restrict__ We, const float* __restrict__ att,
    const float* __restrict__ bias, const float* __restrict__ w_ln,
    const float* __restrict__ Wout,
    unsigned short* __restrict__ outb, float* __restrict__ outf) {
  constexpr int VEC = D / 64;      // channels per lane (8 for D1, 2 for D2)
  constexpr int PAIRS = VEC / 2;   // f32x2 pairs per lane
  const int w = __builtin_amdgcn_readfirstlane(threadIdx.x) >> 6;  // SGPR wave id
  const int n = blockIdx.x * NPB + w;                              // SGPR node
  const int lane = threadIdx.x & 63;
  const int c0 = lane * VEC;

  f32x2 xd2[PAIRS], we2[PAIRS], at2[PAIRS], acc2[PAIRS];
  {
    unsigned int tr[PAIRS];
    if constexpr (PAIRS == 4) {
      uint4 t = *(const uint4*)(xr + (size_t)n * D + c0);
      tr[0] = t.x; tr[1] = t.y; tr[2] = t.z; tr[3] = t.w;
    } else {
      tr[0] = *(const unsigned int*)(xr + (size_t)n * D + c0);
    }
    const f32x2* Wep = (const f32x2*)(We + c0);
    const f32x2* atp = (const f32x2*)(att + c0);
#pragma unroll
    for (int i = 0; i < PAIRS; i++) {
      xd2[i] = bpair(tr[i]);
      we2[i] = Wep[i];
      at2[i] = atp[i];
      acc2[i] = (f32x2){0.f, 0.f};
    }
  }

  const int start = n * CAP;
  const int deg = cnti[n];
  const int total = deg + 1;                    // + self-loop
  const float lan = lsum[n] / fmaxf((float)deg, 1.0f);
  float denom = 0.f;
  const int nfull = total >> 2;                 // wave-uniform
  const int rem = total & 3;

  // one 4-edge chunk; mask is a compile-time-constant bool at both call sites
  auto chunk = [&](int base, bool mask) {
    int s[4]; float eav[4], wgt[4];
#pragma unroll
    for (int k = 0; k < 4; k++) {
      int idx = base + k;
      if (idx < deg) { int2 e = se[start + idx]; s[k] = e.x; eav[k] = __int_as_float(e.y); }
      else           { s[k] = n; eav[k] = lan; }
      if (mask) wgt[k] = (idx < total) ? 1.f : 0.f;
    }
    unsigned int uu[4][PAIRS];
#pragma unroll
    for (int k = 0; k < 4; k++) {                  // 4 gathers in flight
      if constexpr (PAIRS == 4) {
        uint4 t = *(const uint4*)(xl + (size_t)s[k] * D + c0);
        uu[k][0] = t.x; uu[k][1] = t.y; uu[k][2] = t.z; uu[k][3] = t.w;
      } else {
        uu[k][0] = *(const unsigned int*)(xl + (size_t)s[k] * D + c0);
      }
    }
    f32x2 xs2[4][PAIRS];
    f32x2 p2[4];
#pragma unroll
    for (int j = 0; j < 4; j++) p2[j] = (f32x2){0.f, 0.f};
#pragma unroll
    for (int i = 0; i < PAIRS; i++) {
#pragma unroll
      for (int j = 0; j < 4; j++) {
        f32x2 xs = bpair(uu[j][i]);
        xs2[j][i] = xs;
        f32x2 ea = {eav[j], eav[j]};
        f32x2 q = __builtin_elementwise_fma(ea, we2[i], xd2[i]) + xs;  // pk_fma + pk_add
        f32x2 ql = __builtin_elementwise_max(q, q * 0.2f);             // pk_mul + 2*max
        p2[j] = __builtin_elementwise_fma(at2[i], ql, p2[j]);          // pk_fma
      }
    }
    float p[4];
#pragma unroll
    for (int j = 0; j < 4; j++) p[j] = p2[j].x + p2[j].y;
#pragma unroll
    for (int o = 16; o > 0; o >>= 1) {           // half-wave butterfly, 4 chains
#pragma unroll
      for (int j = 0; j < 4; j++) p[j] += __shfl_xor(p[j], o);
    }
    float pe[4];
#pragma unroll
    for (int j = 0; j < 4; j++) {
      pe[j] = __expf(p[j]);
      if (mask) pe[j] *= wgt[j];
      denom += pe[j];
    }
#pragma unroll
    for (int i = 0; i < PAIRS; i++) {
#pragma unroll
      for (int j = 0; j < 4; j++) {
        f32x2 pv = {pe[j], pe[j]};
        acc2[i] = __builtin_elementwise_fma(pv, xs2[j][i], acc2[i]);   // pk_fma
      }
    }
  };

  for (int it = 0; it < nfull; ++it) chunk(it * 4, false);
  if (rem) chunk(nfull * 4, true);

  float inv = 1.f / denom;                       // per-head (per half-wave)
  float vv[VEC], ss = 0.f;
#pragma unroll
  for (int i = 0; i < PAIRS; i++) {
#pragma unroll
    for (int h = 0; h < 2; h++) {
      int k = i * 2 + h;
      float v = fmaf(acc2[i][h], inv, bias[c0 + k]);
      if (DO_SILU) v = v / (1.f + __expf(-v));
      vv[k] = v;
      ss += v * v;
    }
  }
#pragma unroll
  for (int o = 32; o > 0; o >>= 1) ss += __shfl_xor(ss, o);   // full-wave
  float rinv = rsqrtf(ss / (float)D + 1e-5f);

  __shared__ __align__(16) float hrow[NPB][D2];
#pragma unroll
  for (int k = 0; k < VEC; k++) {
    float o = vv[k] * rinv * w_ln[c0 + k];
    if (OBF) outb[(size_t)n * D + c0 + k] = f2b(o);
    if (HEAD_GEMM) hrow[w][c0 + k] = o;
  }
  if (HEAD_GEMM) {
    __syncthreads();                             // no early returns: NN % NPB == 0
    int t = threadIdx.x;
    if (t < NPB * NCLS) {
      int n4 = t / NCLS, c = t % NCLS;
      const float4* wr = (const float4*)(Wout + c * D2);
      const float4* hr = (const float4*)&hrow[n4][0];
      float sm = 0.f;
#pragma unroll
      for (int q = 0; q < D2 / 4; q++) {
        float4 a = hr[q], b = wr[q];
        sm += a.x * b.x + a.y * b.y + a.z * b.z + a.w * b.w;
      }
      outf[(size_t)(blockIdx.x * NPB + n4) * NCLS + c] = sm;
    }
  }
}

// ---------------------------------------------------------------- launch
extern "C" void kernel_launch(void* const* d_in, const int* in_sizes, int n_in,
                              void* d_out, int out_size, void* d_ws, size_t ws_size,
                              hipStream_t stream) {
  const float* x     = (const float*)d_in[0];
  const int*   ei    = (const int*)  d_in[1];
  const float* eattr = (const float*)d_in[2];
  const float* Wl1   = (const float*)d_in[3];
  const float* bl1   = (const float*)d_in[4];
  const float* Wr1   = (const float*)d_in[5];
  const float* br1   = (const float*)d_in[6];
  const float* We1   = (const float*)d_in[7];
  const float* att1  = (const float*)d_in[8];
  const float* bias1 = (const float*)d_in[9];
  const float* Wl2   = (const float*)d_in[10];
  const float* bl2   = (const float*)d_in[11];
  const float* Wr2   = (const float*)d_in[12];
  const float* br2   = (const float*)d_in[13];
  const float* We2   = (const float*)d_in[14];
  const float* att2  = (const float*)d_in[15];
  const float* bias2 = (const float*)d_in[16];
  const float* w_ln1 = (const float*)d_in[17];
  const float* w_ln3 = (const float*)d_in[18];
  const float* W_out = (const float*)d_in[19];
  float* out = (float*)d_out;
  (void)in_sizes; (void)n_in; (void)out_size; (void)ws_size;

  const int* src = ei;
  const int* dst = ei + NE;

  char* wsp = (char*)d_ws;
  auto alloc = [&](size_t nbytes) {
    char* ptr = wsp;
    wsp += ((nbytes + 255) / 256) * 256;
    return ptr;
  };
  int*   cnti   = (int*)  alloc((size_t)NN * 4);   // } contiguous (NNP ints each),
  float* lsum   = (float*)alloc((size_t)NN * 4);   // } zeroed via one hipMemsetAsync
  int2*  se     = (int2*) alloc((size_t)NN * CAP * 8);   // padded CSR (15.4 MB)
  unsigned short* xb   = (unsigned short*)alloc((size_t)NN * D2 * 2);
  unsigned short* Wc1  = (unsigned short*)alloc((size_t)2 * D1 * D2 * 2);
  unsigned short* Wc2  = (unsigned short*)alloc((size_t)2 * D2 * D1 * 2);
  unsigned short* xl1  = (unsigned short*)alloc((size_t)NN * D1 * 2);  // gather table
  unsigned short* xr1  = (unsigned short*)alloc((size_t)NN * D1 * 2);
  unsigned short* h1b  = (unsigned short*)alloc((size_t)NN * D1 * 2);
  unsigned short* xl2  = (unsigned short*)alloc((size_t)NN * D2 * 2);
  unsigned short* xr2  = (unsigned short*)alloc((size_t)NN * D2 * 2);

  // --- preamble: memset + fused cast/CSR-build ---
  hipMemsetAsync(cnti, 0, (size_t)2 * NNP * 4, stream);
  k_build<<<(IDG_TOT + 255) / 256, 256, 0, stream>>>(
      x, Wl1, Wr1, Wl2, Wr2, src, dst, eattr, cnti, lsum, se, xb, Wc1, Wc2);

  const int GB = NN / NPB;           // 1875 gat blocks, 16 nodes (waves) each
  const int MB = (NN + 127) / 128;   // 235 row-tiles

  // --- layer 1: [xl1|xr1] = x @ [Wl1;Wr1]^T + [bl1;br1]  (split bf16 out) ---
  gemm_mfma<128, 4, 64><<<dim3(2 * D1 / 128, MB), 256, 0, stream>>>(
      xb, Wc1, bl1, br1, D1, xl1, xr1, NN, 2 * D1, D2);
  k_gat_node<D1, true, true, false><<<GB, NPB * 64, 0, stream>>>(
      se, cnti, lsum, xl1, xr1, We1, att1, bias1, w_ln1, nullptr, h1b, nullptr);

  // --- layer 2: [xl2|xr2] = h1 @ [Wl2;Wr2]^T + [bl2;br2]  (split bf16 out) ---
  // BK=128: halves K-steps (8->4) and barrier drains; grid 470 blocks <2/CU so
  // the 64 KB LDS cannot cost occupancy here.
  gemm_mfma<128, 4, 128><<<dim3(2 * D2 / 128, MB), 256, 0, stream>>>(
      h1b, Wc2, bl2, br2, D2, xl2, xr2, NN, 2 * D2, D1);
  k_gat_node<D2, false, false, true><<<GB, NPB * 64, 0, stream>>>(
      se, cnti, lsum, xl2, xr2, We2, att2, bias2, w_ln3, W_out, nullptr, out);
}

// Round 6
// 325.939 us; speedup vs baseline: 1.4652x; 1.4652x over previous
//
#include <hip/hip_runtime.h>
#include <cstddef>

#define NN   30000
#define NNP  30016          /* NN ints rounded to 256B alloc granularity */
#define NE   240000
#define D1   512
#define D2   128
#define NCLS 20
#define CAP  64             /* padded-CSR slots per node; Poisson(8) tail @64 ~ 1e-38 */
#define NPB  16             /* nodes (=waves) per gat block; NN % NPB == 0 */
#define CAST_TOT 1025536          /* x(960000) + 4 weights(16384 ea), float4 units */
#define IDG_TOT  (CAST_TOT + NE)  /* + one thread per edge for CSR-build atomics */

typedef __attribute__((ext_vector_type(8))) short short8;
typedef __attribute__((ext_vector_type(4))) float f32x4;
typedef __attribute__((ext_vector_type(2))) float f32x2;

__device__ __forceinline__ unsigned short f2b(float f) {
  union { float f; unsigned int u; } c; c.f = f;
  unsigned int r = (c.u + 0x7fff + ((c.u >> 16) & 1)) >> 16;  // RNE
  return (unsigned short)r;
}
__device__ __forceinline__ float b2f(unsigned short u) {
  union { unsigned int u; float f; } c; c.u = (unsigned int)u << 16;
  return c.f;
}
// two packed bf16 (little-endian: low half = even channel) -> f32x2
__device__ __forceinline__ f32x2 bpair(unsigned int t) {
  f32x2 r;
  r.x = __uint_as_float(t << 16);
  r.y = __uint_as_float(t & 0xffff0000u);
  return r;
}

// ---------------------------------------------------------------- cast + padded-CSR build
// Single kernel replaces initdeg+scan+fill. Edges land directly in
// se_pad[d*CAP + atomicAdd(cnti[d])]; within-node order is atomic-
// nondeterministic — same class as the old cursor-atomic fill (absmax stable
// across 6 rounds). lsum accumulated here; la computed in gat prologue.
__global__ __launch_bounds__(256) void k_build(
    const float* __restrict__ x,
    const float* __restrict__ Wl1, const float* __restrict__ Wr1,
    const float* __restrict__ Wl2, const float* __restrict__ Wr2,
    const int* __restrict__ src, const int* __restrict__ dst,
    const float* __restrict__ eattr,
    int* __restrict__ cnti, float* __restrict__ lsum,
    int2* __restrict__ se,
    unsigned short* __restrict__ xb,
    unsigned short* __restrict__ Wc1, unsigned short* __restrict__ Wc2) {
  int i = blockIdx.x * 256 + threadIdx.x;
  if (i >= IDG_TOT) return;
  if (i >= CAST_TOT) {                 // CSR build + loop-attr atomics
    int e = i - CAST_TOT;
    int d = dst[e];
    int pos = atomicAdd(&cnti[d], 1);
    if (pos < CAP) se[(size_t)d * CAP + pos] = make_int2(src[e], __float_as_int(eattr[e]));
    atomicAdd(&lsum[d], eattr[e]);
    return;
  }
  const float* in; unsigned short* outp; int off;
  if      (i <  960000) { in = x;   outp = xb;          off = i; }
  else if (i <  976384) { in = Wl1; outp = Wc1;         off = i -  960000; }
  else if (i <  992768) { in = Wr1; outp = Wc1 + 65536; off = i -  976384; }
  else if (i < 1009152) { in = Wl2; outp = Wc2;         off = i -  992768; }
  else                  { in = Wr2; outp = Wc2 + 65536; off = i - 1009152; }
  float4 v = ((const float4*)in)[off];
  ushort4 o;
  o.x = f2b(v.x); o.y = f2b(v.y); o.z = f2b(v.z); o.w = f2b(v.w);
  ((ushort4*)outp)[off] = o;
}

// ---------------------------------------------------------------- bf16 MFMA GEMM
// [Cl|Cr][m,n] = sum_k A[m,k]*W[n,k] + bias, W = [Wl;Wr] concat in n; split out.
// m97-style staging: UNPADDED LDS, global_load_lds width=16 — wave covers
// 512/BK rows per issue; dest is wave-uniform base + lane*16 (lane-contiguous).
// BK is a template param: gemm1 (K=128, 1880 blocks) keeps BK=64 (32 KB LDS,
// ~5 wg/CU residency); gemm2 (K=512, 470 blocks <2/CU anyway) uses BK=128 to
// halve barrier-drain rounds (m132's occupancy penalty cannot bind there).
// No OOB row guard: reads past M land in later workspace buffers (no fault);
// garbage only contaminates rows >= M, which the epilogue store masks.
template <int BN, int NT, int BK>   // NT = BN/32 n-tiles per wave
__global__ __launch_bounds__(256) void gemm_mfma(
    const unsigned short* __restrict__ A, const unsigned short* __restrict__ W,
    const float* __restrict__ bl, const float* __restrict__ br, int Nhalf,
    unsigned short* __restrict__ Cl, unsigned short* __restrict__ Cr,
    int M, int N, int K) {
  constexpr int BM = 128, LDK = BK;    // unpadded (global_load_lds)
  constexpr int RPI = 512 / BK;        // rows per wave per load issue (8@64, 4@128)
  constexpr int LPR = BK / 8;          // lanes per row (8@64, 16@128)
  __shared__ __align__(16) unsigned short As[BM * LDK];
  __shared__ __align__(16) unsigned short Bs[BN * LDK];
  const int bm = blockIdx.y * BM;
  const int bn = blockIdx.x * BN;
  const int tid = threadIdx.x;
  const int lane = tid & 63;
  const int wid = __builtin_amdgcn_readfirstlane(tid >> 6);  // wave-uniform (SGPR)
  const int wm = (wid >> 1) * 64;
  const int wn = (wid & 1) * (NT * 16);
  const int l16 = lane & 15, lq = lane >> 4;
  const int lrow = lane / LPR;         // staging: row within RPI
  const int lcol = (lane % LPR) * 8;   // staging: k-offset (8 bf16 = 16 B)

  f32x4 acc[4][NT];
#pragma unroll
  for (int i = 0; i < 4; ++i)
#pragma unroll
    for (int j = 0; j < NT; ++j) acc[i][j] = (f32x4){0.f, 0.f, 0.f, 0.f};

  for (int k0 = 0; k0 < K; k0 += BK) {
#pragma unroll
    for (int p = 0; p < BM / (4 * RPI); ++p) {
      int r = p * (4 * RPI) + wid * RPI;
      const unsigned short* gp = A + (size_t)(bm + r + lrow) * K + k0 + lcol;
      __builtin_amdgcn_global_load_lds(
          (const __attribute__((address_space(1))) unsigned int*)gp,
          (__attribute__((address_space(3))) unsigned int*)(As + (size_t)r * LDK),
          16, 0, 0);
    }
#pragma unroll
    for (int p = 0; p < BN / (4 * RPI); ++p) {
      int r = p * (4 * RPI) + wid * RPI;
      const unsigned short* gp = W + (size_t)(bn + r + lrow) * K + k0 + lcol;
      __builtin_amdgcn_global_load_lds(
          (const __attribute__((address_space(1))) unsigned int*)gp,
          (__attribute__((address_space(3))) unsigned int*)(Bs + (size_t)r * LDK),
          16, 0, 0);
    }
    __syncthreads();
#pragma unroll
    for (int kh = 0; kh < BK / 32; ++kh) {
      short8 af[4], bfr[NT];
#pragma unroll
      for (int mt = 0; mt < 4; ++mt)
        af[mt] = *(const short8*)&As[(wm + mt * 16 + l16) * LDK + kh * 32 + lq * 8];
#pragma unroll
      for (int nt = 0; nt < NT; ++nt)
        bfr[nt] = *(const short8*)&Bs[(wn + nt * 16 + l16) * LDK + kh * 32 + lq * 8];
#pragma unroll
      for (int mt = 0; mt < 4; ++mt)
#pragma unroll
        for (int nt = 0; nt < NT; ++nt)
          acc[mt][nt] = __builtin_amdgcn_mfma_f32_16x16x32_bf16(
              af[mt], bfr[nt], acc[mt][nt], 0, 0, 0);
    }
    __syncthreads();
  }

#pragma unroll
  for (int mt = 0; mt < 4; ++mt)
#pragma unroll
    for (int nt = 0; nt < NT; ++nt) {
      int col = bn + wn + nt * 16 + l16;
      bool left = col < Nhalf;                 // uniform: 64-col strips
      int cc = left ? col : col - Nhalf;
      float b = left ? bl[cc] : br[cc];
      unsigned short* Cp = left ? Cl : Cr;
#pragma unroll
      for (int r = 0; r < 4; ++r) {
        int row = bm + wm + mt * 16 + lq * 4 + r;
        if (row < M) Cp[(size_t)row * Nhalf + cc] = f2b(acc[mt][nt][r] + b);
      }
    }
}

// ---------------------------------------------------------------- fused GATv2 aggregate
// ONE wave per destination node, both heads (lanes [0,32)=h0, [32,64)=h1).
// Per-edge logit: 5-stage half-wave butterfly serves both heads at once.
// 4 edges/iteration; packed f32x2 VOP3P math; wgt-mask only in tail chunk.
// NPB=16 (1024 threads): with 4-wave blocks the CP dispatch rate (~117 wg/us)
// capped residency at ~10 waves/CU (R4: occupancy 31%, Little's law closes);
// 16-wave blocks cut wg count 7500->1875 -> residency slot-limited instead.
// R6: __launch_bounds__(1024) ONLY — R5's ",8" min-waves clamp made the
// compiler pin VGPR=32 and spill everything (WRITE_SIZE 30->474 MB, 3.7x dur).
// Natural allocation is ~56-60 VGPR <= 64, which still fits 8 waves/EU.
template <int D, bool DO_SILU, bool OBF, bool HEAD_GEMM>
__global__ __launch_bounds__(1024) void k_gat_node(
    const int2* __restrict__ se,
    const int* __restrict__ cnti, const float* __restrict__ lsum,
    const unsigned short* __restrict__ xl, const unsigned short* __restrict__ xr,
    const float* __restrict__ We, const float* __restrict__ att,
    const float* __restrict__ bias, const float* __restrict__ w_ln,
    const float* __restrict__ Wout,
    unsigned short* __restrict__ outb, float* __restrict__ outf) {
  constexpr int VEC = D / 64;      // channels per lane (8 for D1, 2 for D2)
  constexpr int PAIRS = VEC / 2;   // f32x2 pairs per lane
  const int w = __builtin_amdgcn_readfirstlane(threadIdx.x) >> 6;  // SGPR wave id
  const int n = blockIdx.x * NPB + w;                              // SGPR node
  const int lane = threadIdx.x & 63;
  const int c0 = lane * VEC;

  f32x2 xd2[PAIRS], we2[PAIRS], at2[PAIRS], acc2[PAIRS];
  {
    unsigned int tr[PAIRS];
    if constexpr (PAIRS == 4) {
      uint4 t = *(const uint4*)(xr + (size_t)n * D + c0);
      tr[0] = t.x; tr[1] = t.y; tr[2] = t.z; tr[3] = t.w;
    } else {
      tr[0] = *(const unsigned int*)(xr + (size_t)n * D + c0);
    }
    const f32x2* Wep = (const f32x2*)(We + c0);
    const f32x2* atp = (const f32x2*)(att + c0);
#pragma unroll
    for (int i = 0; i < PAIRS; i++) {
      xd2[i] = bpair(tr[i]);
      we2[i] = Wep[i];
      at2[i] = atp[i];
      acc2[i] = (f32x2){0.f, 0.f};
    }
  }

  const int start = n * CAP;
  const int deg = cnti[n];
  const int total = deg + 1;                    // + self-loop
  const float lan = lsum[n] / fmaxf((float)deg, 1.0f);
  float denom = 0.f;
  const int nfull = total >> 2;                 // wave-uniform
  const int rem = total & 3;

  // one 4-edge chunk; mask is a compile-time-constant bool at both call sites
  auto chunk = [&](int base, bool mask) {
    int s[4]; float eav[4], wgt[4];
#pragma unroll
    for (int k = 0; k < 4; k++) {
      int idx = base + k;
      if (idx < deg) { int2 e = se[start + idx]; s[k] = e.x; eav[k] = __int_as_float(e.y); }
      else           { s[k] = n; eav[k] = lan; }
      if (mask) wgt[k] = (idx < total) ? 1.f : 0.f;
    }
    unsigned int uu[4][PAIRS];
#pragma unroll
    for (int k = 0; k < 4; k++) {                  // 4 gathers in flight
      if constexpr (PAIRS == 4) {
        uint4 t = *(const uint4*)(xl + (size_t)s[k] * D + c0);
        uu[k][0] = t.x; uu[k][1] = t.y; uu[k][2] = t.z; uu[k][3] = t.w;
      } else {
        uu[k][0] = *(const unsigned int*)(xl + (size_t)s[k] * D + c0);
      }
    }
    f32x2 xs2[4][PAIRS];
    f32x2 p2[4];
#pragma unroll
    for (int j = 0; j < 4; j++) p2[j] = (f32x2){0.f, 0.f};
#pragma unroll
    for (int i = 0; i < PAIRS; i++) {
#pragma unroll
      for (int j = 0; j < 4; j++) {
        f32x2 xs = bpair(uu[j][i]);
        xs2[j][i] = xs;
        f32x2 ea = {eav[j], eav[j]};
        f32x2 q = __builtin_elementwise_fma(ea, we2[i], xd2[i]) + xs;  // pk_fma + pk_add
        f32x2 ql = __builtin_elementwise_max(q, q * 0.2f);             // pk_mul + 2*max
        p2[j] = __builtin_elementwise_fma(at2[i], ql, p2[j]);          // pk_fma
      }
    }
    float p[4];
#pragma unroll
    for (int j = 0; j < 4; j++) p[j] = p2[j].x + p2[j].y;
#pragma unroll
    for (int o = 16; o > 0; o >>= 1) {           // half-wave butterfly, 4 chains
#pragma unroll
      for (int j = 0; j < 4; j++) p[j] += __shfl_xor(p[j], o);
    }
    float pe[4];
#pragma unroll
    for (int j = 0; j < 4; j++) {
      pe[j] = __expf(p[j]);
      if (mask) pe[j] *= wgt[j];
      denom += pe[j];
    }
#pragma unroll
    for (int i = 0; i < PAIRS; i++) {
#pragma unroll
      for (int j = 0; j < 4; j++) {
        f32x2 pv = {pe[j], pe[j]};
        acc2[i] = __builtin_elementwise_fma(pv, xs2[j][i], acc2[i]);   // pk_fma
      }
    }
  };

  for (int it = 0; it < nfull; ++it) chunk(it * 4, false);
  if (rem) chunk(nfull * 4, true);

  float inv = 1.f / denom;                       // per-head (per half-wave)
  float vv[VEC], ss = 0.f;
#pragma unroll
  for (int i = 0; i < PAIRS; i++) {
#pragma unroll
    for (int h = 0; h < 2; h++) {
      int k = i * 2 + h;
      float v = fmaf(acc2[i][h], inv, bias[c0 + k]);
      if (DO_SILU) v = v / (1.f + __expf(-v));
      vv[k] = v;
      ss += v * v;
    }
  }
#pragma unroll
  for (int o = 32; o > 0; o >>= 1) ss += __shfl_xor(ss, o);   // full-wave
  float rinv = rsqrtf(ss / (float)D + 1e-5f);

  __shared__ __align__(16) float hrow[NPB][D2];
#pragma unroll
  for (int k = 0; k < VEC; k++) {
    float o = vv[k] * rinv * w_ln[c0 + k];
    if (OBF) outb[(size_t)n * D + c0 + k] = f2b(o);
    if (HEAD_GEMM) hrow[w][c0 + k] = o;
  }
  if (HEAD_GEMM) {
    __syncthreads();                             // no early returns: NN % NPB == 0
    int t = threadIdx.x;
    if (t < NPB * NCLS) {
      int n4 = t / NCLS, c = t % NCLS;
      const float4* wr = (const float4*)(Wout + c * D2);
      const float4* hr = (const float4*)&hrow[n4][0];
      float sm = 0.f;
#pragma unroll
      for (int q = 0; q < D2 / 4; q++) {
        float4 a = hr[q], b = wr[q];
        sm += a.x * b.x + a.y * b.y + a.z * b.z + a.w * b.w;
      }
      outf[(size_t)(blockIdx.x * NPB + n4) * NCLS + c] = sm;
    }
  }
}

// ---------------------------------------------------------------- launch
extern "C" void kernel_launch(void* const* d_in, const int* in_sizes, int n_in,
                              void* d_out, int out_size, void* d_ws, size_t ws_size,
                              hipStream_t stream) {
  const float* x     = (const float*)d_in[0];
  const int*   ei    = (const int*)  d_in[1];
  const float* eattr = (const float*)d_in[2];
  const float* Wl1   = (const float*)d_in[3];
  const float* bl1   = (const float*)d_in[4];
  const float* Wr1   = (const float*)d_in[5];
  const float* br1   = (const float*)d_in[6];
  const float* We1   = (const float*)d_in[7];
  const float* att1  = (const float*)d_in[8];
  const float* bias1 = (const float*)d_in[9];
  const float* Wl2   = (const float*)d_in[10];
  const float* bl2   = (const float*)d_in[11];
  const float* Wr2   = (const float*)d_in[12];
  const float* br2   = (const float*)d_in[13];
  const float* We2   = (const float*)d_in[14];
  const float* att2  = (const float*)d_in[15];
  const float* bias2 = (const float*)d_in[16];
  const float* w_ln1 = (const float*)d_in[17];
  const float* w_ln3 = (const float*)d_in[18];
  const float* W_out = (const float*)d_in[19];
  float* out = (float*)d_out;
  (void)in_sizes; (void)n_in; (void)out_size; (void)ws_size;

  const int* src = ei;
  const int* dst = ei + NE;

  char* wsp = (char*)d_ws;
  auto alloc = [&](size_t nbytes) {
    char* ptr = wsp;
    wsp += ((nbytes + 255) / 256) * 256;
    return ptr;
  };
  int*   cnti   = (int*)  alloc((size_t)NN * 4);   // } contiguous (NNP ints each),
  float* lsum   = (float*)alloc((size_t)NN * 4);   // } zeroed via one hipMemsetAsync
  int2*  se     = (int2*) alloc((size_t)NN * CAP * 8);   // padded CSR (15.4 MB)
  unsigned short* xb   = (unsigned short*)alloc((size_t)NN * D2 * 2);
  unsigned short* Wc1  = (unsigned short*)alloc((size_t)2 * D1 * D2 * 2);
  unsigned short* Wc2  = (unsigned short*)alloc((size_t)2 * D2 * D1 * 2);
  unsigned short* xl1  = (unsigned short*)alloc((size_t)NN * D1 * 2);  // gather table
  unsigned short* xr1  = (unsigned short*)alloc((size_t)NN * D1 * 2);
  unsigned short* h1b  = (unsigned short*)alloc((size_t)NN * D1 * 2);
  unsigned short* xl2  = (unsigned short*)alloc((size_t)NN * D2 * 2);
  unsigned short* xr2  = (unsigned short*)alloc((size_t)NN * D2 * 2);

  // --- preamble: memset + fused cast/CSR-build ---
  hipMemsetAsync(cnti, 0, (size_t)2 * NNP * 4, stream);
  k_build<<<(IDG_TOT + 255) / 256, 256, 0, stream>>>(
      x, Wl1, Wr1, Wl2, Wr2, src, dst, eattr, cnti, lsum, se, xb, Wc1, Wc2);

  const int GB = NN / NPB;           // 1875 gat blocks, 16 nodes (waves) each
  const int MB = (NN + 127) / 128;   // 235 row-tiles

  // --- layer 1: [xl1|xr1] = x @ [Wl1;Wr1]^T + [bl1;br1]  (split bf16 out) ---
  gemm_mfma<128, 4, 64><<<dim3(2 * D1 / 128, MB), 256, 0, stream>>>(
      xb, Wc1, bl1, br1, D1, xl1, xr1, NN, 2 * D1, D2);
  k_gat_node<D1, true, true, false><<<GB, NPB * 64, 0, stream>>>(
      se, cnti, lsum, xl1, xr1, We1, att1, bias1, w_ln1, nullptr, h1b, nullptr);

  // --- layer 2: [xl2|xr2] = h1 @ [Wl2;Wr2]^T + [bl2;br2]  (split bf16 out) ---
  // BK=128: halves K-steps (8->4) and barrier drains; grid 470 blocks <2/CU so
  // the 64 KB LDS cannot cost occupancy here.
  gemm_mfma<128, 4, 128><<<dim3(2 * D2 / 128, MB), 256, 0, stream>>>(
      h1b, Wc2, bl2, br2, D2, xl2, xr2, NN, 2 * D2, D1);
  k_gat_node<D2, false, false, true><<<GB, NPB * 64, 0, stream>>>(
      se, cnti, lsum, xl2, xr2, We2, att2, bias2, w_ln3, W_out, nullptr, out);
}

// Round 7
// 295.472 us; speedup vs baseline: 1.6163x; 1.1031x over previous
//
#include <hip/hip_runtime.h>
#include <cstddef>

#define NN   30000
#define NNP  30016          /* NN ints rounded to 256B alloc granularity */
#define NE   240000
#define D1   512
#define D2   128
#define NCLS 20
#define CAP  64             /* padded-CSR slots per node; Poisson(8) tail @64 ~ 1e-38 */
#define CAST_TOT 1025536          /* x(960000) + 4 weights(16384 ea), float4 units */
#define IDG_TOT  (CAST_TOT + NE)  /* + one thread per edge for CSR-build atomics */

typedef __attribute__((ext_vector_type(8))) short short8;
typedef __attribute__((ext_vector_type(4))) float f32x4;
typedef __attribute__((ext_vector_type(2))) float f32x2;

__device__ __forceinline__ unsigned short f2b(float f) {
  union { float f; unsigned int u; } c; c.f = f;
  unsigned int r = (c.u + 0x7fff + ((c.u >> 16) & 1)) >> 16;  // RNE
  return (unsigned short)r;
}
__device__ __forceinline__ float b2f(unsigned short u) {
  union { unsigned int u; float f; } c; c.u = (unsigned int)u << 16;
  return c.f;
}
// two packed bf16 (little-endian: low half = even channel) -> f32x2
__device__ __forceinline__ f32x2 bpair(unsigned int t) {
  f32x2 r;
  r.x = __uint_as_float(t << 16);
  r.y = __uint_as_float(t & 0xffff0000u);
  return r;
}

// ---------------------------------------------------------------- cast + padded-CSR build
// Single kernel replaces initdeg+scan+fill. Edges land directly in
// se_pad[d*CAP + atomicAdd(cnti[d])]; within-node order is atomic-
// nondeterministic — same class as the old cursor-atomic fill (absmax stable
// across 7 rounds). lsum accumulated here; la computed in gat prologue.
__global__ __launch_bounds__(256) void k_build(
    const float* __restrict__ x,
    const float* __restrict__ Wl1, const float* __restrict__ Wr1,
    const float* __restrict__ Wl2, const float* __restrict__ Wr2,
    const int* __restrict__ src, const int* __restrict__ dst,
    const float* __restrict__ eattr,
    int* __restrict__ cnti, float* __restrict__ lsum,
    int2* __restrict__ se,
    unsigned short* __restrict__ xb,
    unsigned short* __restrict__ Wc1, unsigned short* __restrict__ Wc2) {
  int i = blockIdx.x * 256 + threadIdx.x;
  if (i >= IDG_TOT) return;
  if (i >= CAST_TOT) {                 // CSR build + loop-attr atomics
    int e = i - CAST_TOT;
    int d = dst[e];
    int pos = atomicAdd(&cnti[d], 1);
    if (pos < CAP) se[(size_t)d * CAP + pos] = make_int2(src[e], __float_as_int(eattr[e]));
    atomicAdd(&lsum[d], eattr[e]);
    return;
  }
  const float* in; unsigned short* outp; int off;
  if      (i <  960000) { in = x;   outp = xb;          off = i; }
  else if (i <  976384) { in = Wl1; outp = Wc1;         off = i -  960000; }
  else if (i <  992768) { in = Wr1; outp = Wc1 + 65536; off = i -  976384; }
  else if (i < 1009152) { in = Wl2; outp = Wc2;         off = i -  992768; }
  else                  { in = Wr2; outp = Wc2 + 65536; off = i - 1009152; }
  float4 v = ((const float4*)in)[off];
  ushort4 o;
  o.x = f2b(v.x); o.y = f2b(v.y); o.z = f2b(v.z); o.w = f2b(v.w);
  ((ushort4*)outp)[off] = o;
}

// ---------------------------------------------------------------- bf16 MFMA GEMM
// [Cl|Cr][m,n] = sum_k A[m,k]*W[n,k] + bias, W = [Wl;Wr] concat in n; split out.
// m97-style staging: UNPADDED LDS, global_load_lds width=16 — wave covers
// 512/BK rows per issue; dest is wave-uniform base + lane*16 (lane-contiguous).
// BK=64 for both layers (R4 config, best measured). BK=128 never cleanly
// isolated (R5/R6 confounded by gat spills/blocks); keep one variable/round.
// No OOB row guard: reads past M land in later workspace buffers (no fault);
// garbage only contaminates rows >= M, which the epilogue store masks.
template <int BN, int NT, int BK>   // NT = BN/32 n-tiles per wave
__global__ __launch_bounds__(256) void gemm_mfma(
    const unsigned short* __restrict__ A, const unsigned short* __restrict__ W,
    const float* __restrict__ bl, const float* __restrict__ br, int Nhalf,
    unsigned short* __restrict__ Cl, unsigned short* __restrict__ Cr,
    int M, int N, int K) {
  constexpr int BM = 128, LDK = BK;    // unpadded (global_load_lds)
  constexpr int RPI = 512 / BK;        // rows per wave per load issue (8@64)
  constexpr int LPR = BK / 8;          // lanes per row (8@64)
  __shared__ __align__(16) unsigned short As[BM * LDK];
  __shared__ __align__(16) unsigned short Bs[BN * LDK];
  const int bm = blockIdx.y * BM;
  const int bn = blockIdx.x * BN;
  const int tid = threadIdx.x;
  const int lane = tid & 63;
  const int wid = __builtin_amdgcn_readfirstlane(tid >> 6);  // wave-uniform (SGPR)
  const int wm = (wid >> 1) * 64;
  const int wn = (wid & 1) * (NT * 16);
  const int l16 = lane & 15, lq = lane >> 4;
  const int lrow = lane / LPR;         // staging: row within RPI
  const int lcol = (lane % LPR) * 8;   // staging: k-offset (8 bf16 = 16 B)

  f32x4 acc[4][NT];
#pragma unroll
  for (int i = 0; i < 4; ++i)
#pragma unroll
    for (int j = 0; j < NT; ++j) acc[i][j] = (f32x4){0.f, 0.f, 0.f, 0.f};

  for (int k0 = 0; k0 < K; k0 += BK) {
#pragma unroll
    for (int p = 0; p < BM / (4 * RPI); ++p) {
      int r = p * (4 * RPI) + wid * RPI;
      const unsigned short* gp = A + (size_t)(bm + r + lrow) * K + k0 + lcol;
      __builtin_amdgcn_global_load_lds(
          (const __attribute__((address_space(1))) unsigned int*)gp,
          (__attribute__((address_space(3))) unsigned int*)(As + (size_t)r * LDK),
          16, 0, 0);
    }
#pragma unroll
    for (int p = 0; p < BN / (4 * RPI); ++p) {
      int r = p * (4 * RPI) + wid * RPI;
      const unsigned short* gp = W + (size_t)(bn + r + lrow) * K + k0 + lcol;
      __builtin_amdgcn_global_load_lds(
          (const __attribute__((address_space(1))) unsigned int*)gp,
          (__attribute__((address_space(3))) unsigned int*)(Bs + (size_t)r * LDK),
          16, 0, 0);
    }
    __syncthreads();
#pragma unroll
    for (int kh = 0; kh < BK / 32; ++kh) {
      short8 af[4], bfr[NT];
#pragma unroll
      for (int mt = 0; mt < 4; ++mt)
        af[mt] = *(const short8*)&As[(wm + mt * 16 + l16) * LDK + kh * 32 + lq * 8];
#pragma unroll
      for (int nt = 0; nt < NT; ++nt)
        bfr[nt] = *(const short8*)&Bs[(wn + nt * 16 + l16) * LDK + kh * 32 + lq * 8];
#pragma unroll
      for (int mt = 0; mt < 4; ++mt)
#pragma unroll
        for (int nt = 0; nt < NT; ++nt)
          acc[mt][nt] = __builtin_amdgcn_mfma_f32_16x16x32_bf16(
              af[mt], bfr[nt], acc[mt][nt], 0, 0, 0);
    }
    __syncthreads();
  }

#pragma unroll
  for (int mt = 0; mt < 4; ++mt)
#pragma unroll
    for (int nt = 0; nt < NT; ++nt) {
      int col = bn + wn + nt * 16 + l16;
      bool left = col < Nhalf;                 // uniform: 64-col strips
      int cc = left ? col : col - Nhalf;
      float b = left ? bl[cc] : br[cc];
      unsigned short* Cp = left ? Cl : Cr;
#pragma unroll
      for (int r = 0; r < 4; ++r) {
        int row = bm + wm + mt * 16 + lq * 4 + r;
        if (row < M) Cp[(size_t)row * Nhalf + cc] = f2b(acc[mt][nt][r] + b);
      }
    }
}

// ---------------------------------------------------------------- fused GATv2 aggregate
// R4 structure (best: 289.4 us): ONE wave per destination node, 4 nodes per
// 256-thread block. R6's 16-wave blocks REGRESSED (intra-block tail idle:
// block holds 16 wave slots until its slowest node finishes; Poisson-degree
// max-of-16 ~ 1.8x mean). Residency equilibrium is ~10 waves/CU regardless of
// wg count (CP-rate theory refuted in R6) -> the lever is per-wave LIFETIME.
// R7: se edge-list register-cache. One predicated coalesced load puts the
// node's edge list in lane registers (deg <= ~30 << 64); per chunk, s[k]/ea[k]
// come from readlane (wave-uniform idx -> SGPR result). Removes the ~300cy
// se broadcast-load from every chunk's critical chain AND moves gather
// addressing to SGPR base + lane offset. Numerics identical.
// Keep VGPR <= 64 (R1: >64 halves wave cap; R5: min-waves clamp caused spills).
template <int D, bool DO_SILU, bool OBF, bool HEAD_GEMM>
__global__ __launch_bounds__(256) void k_gat_node(
    const int2* __restrict__ se,
    const int* __restrict__ cnti, const float* __restrict__ lsum,
    const unsigned short* __restrict__ xl, const unsigned short* __restrict__ xr,
    const float* __restrict__ We, const float* __restrict__ att,
    const float* __restrict__ bias, const float* __restrict__ w_ln,
    const float* __restrict__ Wout,
    unsigned short* __restrict__ outb, float* __restrict__ outf) {
  constexpr int VEC = D / 64;      // channels per lane (8 for D1, 2 for D2)
  constexpr int PAIRS = VEC / 2;   // f32x2 pairs per lane
  const int w = __builtin_amdgcn_readfirstlane(threadIdx.x) >> 6;  // SGPR wave id
  const int n = blockIdx.x * 4 + w;                                // SGPR node
  const int lane = threadIdx.x & 63;
  const int c0 = lane * VEC;

  const int start = n * CAP;
  const int deg = cnti[n];                      // SGPR (n uniform)
  const int total = deg + 1;                    // + self-loop
  const float lan = lsum[n] / fmaxf((float)deg, 1.0f);

  // R7: whole edge list -> lane registers (coalesced, touches only ceil(deg/8)
  // cache lines, same footprint as before). Garbage beyond deg never read.
  int2 myse = make_int2(0, 0);
  if (lane < deg) myse = se[start + lane];

  f32x2 xd2[PAIRS], we2[PAIRS], at2[PAIRS], acc2[PAIRS];
  {
    unsigned int tr[PAIRS];
    if constexpr (PAIRS == 4) {
      uint4 t = *(const uint4*)(xr + (size_t)n * D + c0);
      tr[0] = t.x; tr[1] = t.y; tr[2] = t.z; tr[3] = t.w;
    } else {
      tr[0] = *(const unsigned int*)(xr + (size_t)n * D + c0);
    }
    const f32x2* Wep = (const f32x2*)(We + c0);
    const f32x2* atp = (const f32x2*)(att + c0);
#pragma unroll
    for (int i = 0; i < PAIRS; i++) {
      xd2[i] = bpair(tr[i]);
      we2[i] = Wep[i];
      at2[i] = atp[i];
      acc2[i] = (f32x2){0.f, 0.f};
    }
  }

  float denom = 0.f;
  const int nfull = total >> 2;                 // wave-uniform
  const int rem = total & 3;

  // one 4-edge chunk; mask is a compile-time-constant bool at both call sites
  auto chunk = [&](int base, bool mask) {
    int s[4]; float eav[4], wgt[4];
#pragma unroll
    for (int k = 0; k < 4; k++) {
      int idx = base + k;                        // wave-uniform
      int sx = __builtin_amdgcn_readlane(myse.x, idx);   // SGPR
      int sy = __builtin_amdgcn_readlane(myse.y, idx);   // SGPR
      bool in = idx < deg;                       // uniform compare
      s[k] = in ? sx : n;
      eav[k] = in ? __int_as_float(sy) : lan;
      if (mask) wgt[k] = (idx < total) ? 1.f : 0.f;
    }
    unsigned int uu[4][PAIRS];
#pragma unroll
    for (int k = 0; k < 4; k++) {                  // 4 gathers in flight, SGPR base
      if constexpr (PAIRS == 4) {
        uint4 t = *(const uint4*)(xl + (size_t)s[k] * D + c0);
        uu[k][0] = t.x; uu[k][1] = t.y; uu[k][2] = t.z; uu[k][3] = t.w;
      } else {
        uu[k][0] = *(const unsigned int*)(xl + (size_t)s[k] * D + c0);
      }
    }
    f32x2 xs2[4][PAIRS];
    f32x2 p2[4];
#pragma unroll
    for (int j = 0; j < 4; j++) p2[j] = (f32x2){0.f, 0.f};
#pragma unroll
    for (int i = 0; i < PAIRS; i++) {
#pragma unroll
      for (int j = 0; j < 4; j++) {
        f32x2 xs = bpair(uu[j][i]);
        xs2[j][i] = xs;
        f32x2 ea = {eav[j], eav[j]};
        f32x2 q = __builtin_elementwise_fma(ea, we2[i], xd2[i]) + xs;  // pk_fma + pk_add
        f32x2 ql = __builtin_elementwise_max(q, q * 0.2f);             // pk_mul + 2*max
        p2[j] = __builtin_elementwise_fma(at2[i], ql, p2[j]);          // pk_fma
      }
    }
    float p[4];
#pragma unroll
    for (int j = 0; j < 4; j++) p[j] = p2[j].x + p2[j].y;
#pragma unroll
    for (int o = 16; o > 0; o >>= 1) {           // half-wave butterfly, 4 chains
#pragma unroll
      for (int j = 0; j < 4; j++) p[j] += __shfl_xor(p[j], o);
    }
    float pe[4];
#pragma unroll
    for (int j = 0; j < 4; j++) {
      pe[j] = __expf(p[j]);
      if (mask) pe[j] *= wgt[j];
      denom += pe[j];
    }
#pragma unroll
    for (int i = 0; i < PAIRS; i++) {
#pragma unroll
      for (int j = 0; j < 4; j++) {
        f32x2 pv = {pe[j], pe[j]};
        acc2[i] = __builtin_elementwise_fma(pv, xs2[j][i], acc2[i]);   // pk_fma
      }
    }
  };

  for (int it = 0; it < nfull; ++it) chunk(it * 4, false);
  if (rem) chunk(nfull * 4, true);

  float inv = 1.f / denom;                       // per-head (per half-wave)
  float vv[VEC], ss = 0.f;
#pragma unroll
  for (int i = 0; i < PAIRS; i++) {
#pragma unroll
    for (int h = 0; h < 2; h++) {
      int k = i * 2 + h;
      float v = fmaf(acc2[i][h], inv, bias[c0 + k]);
      if (DO_SILU) v = v / (1.f + __expf(-v));
      vv[k] = v;
      ss += v * v;
    }
  }
#pragma unroll
  for (int o = 32; o > 0; o >>= 1) ss += __shfl_xor(ss, o);   // full-wave
  float rinv = rsqrtf(ss / (float)D + 1e-5f);

  __shared__ __align__(16) float hrow[4][D2];
#pragma unroll
  for (int k = 0; k < VEC; k++) {
    float o = vv[k] * rinv * w_ln[c0 + k];
    if (OBF) outb[(size_t)n * D + c0 + k] = f2b(o);
    if (HEAD_GEMM) hrow[w][c0 + k] = o;
  }
  if (HEAD_GEMM) {
    __syncthreads();                             // no early returns: NN % 4 == 0
    int t = threadIdx.x;
    if (t < 4 * NCLS) {
      int n4 = t / NCLS, c = t % NCLS;
      const float4* wr = (const float4*)(Wout + c * D2);
      const float4* hr = (const float4*)&hrow[n4][0];
      float sm = 0.f;
#pragma unroll
      for (int q = 0; q < D2 / 4; q++) {
        float4 a = hr[q], b = wr[q];
        sm += a.x * b.x + a.y * b.y + a.z * b.z + a.w * b.w;
      }
      outf[(size_t)(blockIdx.x * 4 + n4) * NCLS + c] = sm;
    }
  }
}

// ---------------------------------------------------------------- launch
extern "C" void kernel_launch(void* const* d_in, const int* in_sizes, int n_in,
                              void* d_out, int out_size, void* d_ws, size_t ws_size,
                              hipStream_t stream) {
  const float* x     = (const float*)d_in[0];
  const int*   ei    = (const int*)  d_in[1];
  const float* eattr = (const float*)d_in[2];
  const float* Wl1   = (const float*)d_in[3];
  const float* bl1   = (const float*)d_in[4];
  const float* Wr1   = (const float*)d_in[5];
  const float* br1   = (const float*)d_in[6];
  const float* We1   = (const float*)d_in[7];
  const float* att1  = (const float*)d_in[8];
  const float* bias1 = (const float*)d_in[9];
  const float* Wl2   = (const float*)d_in[10];
  const float* bl2   = (const float*)d_in[11];
  const float* Wr2   = (const float*)d_in[12];
  const float* br2   = (const float*)d_in[13];
  const float* We2   = (const float*)d_in[14];
  const float* att2  = (const float*)d_in[15];
  const float* bias2 = (const float*)d_in[16];
  const float* w_ln1 = (const float*)d_in[17];
  const float* w_ln3 = (const float*)d_in[18];
  const float* W_out = (const float*)d_in[19];
  float* out = (float*)d_out;
  (void)in_sizes; (void)n_in; (void)out_size; (void)ws_size;

  const int* src = ei;
  const int* dst = ei + NE;

  char* wsp = (char*)d_ws;
  auto alloc = [&](size_t nbytes) {
    char* ptr = wsp;
    wsp += ((nbytes + 255) / 256) * 256;
    return ptr;
  };
  int*   cnti   = (int*)  alloc((size_t)NN * 4);   // } contiguous (NNP ints each),
  float* lsum   = (float*)alloc((size_t)NN * 4);   // } zeroed via one hipMemsetAsync
  int2*  se     = (int2*) alloc((size_t)NN * CAP * 8);   // padded CSR (15.4 MB)
  unsigned short* xb   = (unsigned short*)alloc((size_t)NN * D2 * 2);
  unsigned short* Wc1  = (unsigned short*)alloc((size_t)2 * D1 * D2 * 2);
  unsigned short* Wc2  = (unsigned short*)alloc((size_t)2 * D2 * D1 * 2);
  unsigned short* xl1  = (unsigned short*)alloc((size_t)NN * D1 * 2);  // gather table
  unsigned short* xr1  = (unsigned short*)alloc((size_t)NN * D1 * 2);
  unsigned short* h1b  = (unsigned short*)alloc((size_t)NN * D1 * 2);
  unsigned short* xl2  = (unsigned short*)alloc((size_t)NN * D2 * 2);
  unsigned short* xr2  = (unsigned short*)alloc((size_t)NN * D2 * 2);

  // --- preamble: memset + fused cast/CSR-build ---
  hipMemsetAsync(cnti, 0, (size_t)2 * NNP * 4, stream);
  k_build<<<(IDG_TOT + 255) / 256, 256, 0, stream>>>(
      x, Wl1, Wr1, Wl2, Wr2, src, dst, eattr, cnti, lsum, se, xb, Wc1, Wc2);

  const int GB = NN / 4;             // 4 nodes/block, 1 wave each (NN % 4 == 0)
  const int MB = (NN + 127) / 128;   // 235 row-tiles

  // --- layer 1: [xl1|xr1] = x @ [Wl1;Wr1]^T + [bl1;br1]  (split bf16 out) ---
  gemm_mfma<128, 4, 64><<<dim3(2 * D1 / 128, MB), 256, 0, stream>>>(
      xb, Wc1, bl1, br1, D1, xl1, xr1, NN, 2 * D1, D2);
  k_gat_node<D1, true, true, false><<<GB, 256, 0, stream>>>(
      se, cnti, lsum, xl1, xr1, We1, att1, bias1, w_ln1, nullptr, h1b, nullptr);

  // --- layer 2: [xl2|xr2] = h1 @ [Wl2;Wr2]^T + [bl2;br2]  (split bf16 out) ---
  gemm_mfma<128, 4, 64><<<dim3(2 * D2 / 128, MB), 256, 0, stream>>>(
      h1b, Wc2, bl2, br2, D2, xl2, xr2, NN, 2 * D2, D1);
  k_gat_node<D2, false, false, true><<<GB, 256, 0, stream>>>(
      se, cnti, lsum, xl2, xr2, We2, att2, bias2, w_ln3, W_out, nullptr, out);
}

// Round 8
// 287.537 us; speedup vs baseline: 1.6609x; 1.0276x over previous
//
#include <hip/hip_runtime.h>
#include <cstddef>

#define NN   30000
#define NNP  30016          /* NN ints rounded to 256B alloc granularity */
#define NE   240000
#define D1   512
#define D2   128
#define NCLS 20
#define CAP  64             /* padded-CSR slots per node; Poisson(8) tail @64 ~ 1e-38 */
#define CAST_TOT 1025536          /* x(960000) + 4 weights(16384 ea), float4 units */
#define IDG_TOT  (CAST_TOT + NE)  /* + one thread per edge for CSR-build atomics */

typedef __attribute__((ext_vector_type(8))) short short8;
typedef __attribute__((ext_vector_type(4))) float f32x4;
typedef __attribute__((ext_vector_type(2))) float f32x2;

__device__ __forceinline__ unsigned short f2b(float f) {
  union { float f; unsigned int u; } c; c.f = f;
  unsigned int r = (c.u + 0x7fff + ((c.u >> 16) & 1)) >> 16;  // RNE
  return (unsigned short)r;
}
__device__ __forceinline__ float b2f(unsigned short u) {
  union { unsigned int u; float f; } c; c.u = (unsigned int)u << 16;
  return c.f;
}
// two packed bf16 (little-endian: low half = even channel) -> f32x2
__device__ __forceinline__ f32x2 bpair(unsigned int t) {
  f32x2 r;
  r.x = __uint_as_float(t << 16);
  r.y = __uint_as_float(t & 0xffff0000u);
  return r;
}

// ---------------------------------------------------------------- cast + padded-CSR build
// Single kernel replaces initdeg+scan+fill. Edges land directly in
// se_pad[d*CAP + atomicAdd(cnti[d])]; within-node order is atomic-
// nondeterministic — same class as the old cursor-atomic fill (absmax stable
// across 8 rounds). lsum accumulated here; la computed in gat prologue.
__global__ __launch_bounds__(256) void k_build(
    const float* __restrict__ x,
    const float* __restrict__ Wl1, const float* __restrict__ Wr1,
    const float* __restrict__ Wl2, const float* __restrict__ Wr2,
    const int* __restrict__ src, const int* __restrict__ dst,
    const float* __restrict__ eattr,
    int* __restrict__ cnti, float* __restrict__ lsum,
    int2* __restrict__ se,
    unsigned short* __restrict__ xb,
    unsigned short* __restrict__ Wc1, unsigned short* __restrict__ Wc2) {
  int i = blockIdx.x * 256 + threadIdx.x;
  if (i >= IDG_TOT) return;
  if (i >= CAST_TOT) {                 // CSR build + loop-attr atomics
    int e = i - CAST_TOT;
    int d = dst[e];
    int pos = atomicAdd(&cnti[d], 1);
    if (pos < CAP) se[(size_t)d * CAP + pos] = make_int2(src[e], __float_as_int(eattr[e]));
    atomicAdd(&lsum[d], eattr[e]);
    return;
  }
  const float* in; unsigned short* outp; int off;
  if      (i <  960000) { in = x;   outp = xb;          off = i; }
  else if (i <  976384) { in = Wl1; outp = Wc1;         off = i -  960000; }
  else if (i <  992768) { in = Wr1; outp = Wc1 + 65536; off = i -  976384; }
  else if (i < 1009152) { in = Wl2; outp = Wc2;         off = i -  992768; }
  else                  { in = Wr2; outp = Wc2 + 65536; off = i - 1009152; }
  float4 v = ((const float4*)in)[off];
  ushort4 o;
  o.x = f2b(v.x); o.y = f2b(v.y); o.z = f2b(v.z); o.w = f2b(v.w);
  ((ushort4*)outp)[off] = o;
}

// ---------------------------------------------------------------- bf16 MFMA GEMM
// [Cl|Cr][m,n] = sum_k A[m,k]*W[n,k] + bias, W = [Wl;Wr] concat in n; split out.
// m97-style staging: UNPADDED LDS, global_load_lds width=16 — wave covers
// 512/BK rows per issue; dest is wave-uniform base + lane*16 (lane-contiguous).
// BK=64 both layers (R4 config).
// No OOB row guard: reads past M land in later workspace buffers (no fault);
// garbage only contaminates rows >= M, which the epilogue store masks.
template <int BN, int NT, int BK>   // NT = BN/32 n-tiles per wave
__global__ __launch_bounds__(256) void gemm_mfma(
    const unsigned short* __restrict__ A, const unsigned short* __restrict__ W,
    const float* __restrict__ bl, const float* __restrict__ br, int Nhalf,
    unsigned short* __restrict__ Cl, unsigned short* __restrict__ Cr,
    int M, int N, int K) {
  constexpr int BM = 128, LDK = BK;    // unpadded (global_load_lds)
  constexpr int RPI = 512 / BK;        // rows per wave per load issue (8@64)
  constexpr int LPR = BK / 8;          // lanes per row (8@64)
  __shared__ __align__(16) unsigned short As[BM * LDK];
  __shared__ __align__(16) unsigned short Bs[BN * LDK];
  const int bm = blockIdx.y * BM;
  const int bn = blockIdx.x * BN;
  const int tid = threadIdx.x;
  const int lane = tid & 63;
  const int wid = __builtin_amdgcn_readfirstlane(tid >> 6);  // wave-uniform (SGPR)
  const int wm = (wid >> 1) * 64;
  const int wn = (wid & 1) * (NT * 16);
  const int l16 = lane & 15, lq = lane >> 4;
  const int lrow = lane / LPR;         // staging: row within RPI
  const int lcol = (lane % LPR) * 8;   // staging: k-offset (8 bf16 = 16 B)

  f32x4 acc[4][NT];
#pragma unroll
  for (int i = 0; i < 4; ++i)
#pragma unroll
    for (int j = 0; j < NT; ++j) acc[i][j] = (f32x4){0.f, 0.f, 0.f, 0.f};

  for (int k0 = 0; k0 < K; k0 += BK) {
#pragma unroll
    for (int p = 0; p < BM / (4 * RPI); ++p) {
      int r = p * (4 * RPI) + wid * RPI;
      const unsigned short* gp = A + (size_t)(bm + r + lrow) * K + k0 + lcol;
      __builtin_amdgcn_global_load_lds(
          (const __attribute__((address_space(1))) unsigned int*)gp,
          (__attribute__((address_space(3))) unsigned int*)(As + (size_t)r * LDK),
          16, 0, 0);
    }
#pragma unroll
    for (int p = 0; p < BN / (4 * RPI); ++p) {
      int r = p * (4 * RPI) + wid * RPI;
      const unsigned short* gp = W + (size_t)(bn + r + lrow) * K + k0 + lcol;
      __builtin_amdgcn_global_load_lds(
          (const __attribute__((address_space(1))) unsigned int*)gp,
          (__attribute__((address_space(3))) unsigned int*)(Bs + (size_t)r * LDK),
          16, 0, 0);
    }
    __syncthreads();
#pragma unroll
    for (int kh = 0; kh < BK / 32; ++kh) {
      short8 af[4], bfr[NT];
#pragma unroll
      for (int mt = 0; mt < 4; ++mt)
        af[mt] = *(const short8*)&As[(wm + mt * 16 + l16) * LDK + kh * 32 + lq * 8];
#pragma unroll
      for (int nt = 0; nt < NT; ++nt)
        bfr[nt] = *(const short8*)&Bs[(wn + nt * 16 + l16) * LDK + kh * 32 + lq * 8];
#pragma unroll
      for (int mt = 0; mt < 4; ++mt)
#pragma unroll
        for (int nt = 0; nt < NT; ++nt)
          acc[mt][nt] = __builtin_amdgcn_mfma_f32_16x16x32_bf16(
              af[mt], bfr[nt], acc[mt][nt], 0, 0, 0);
    }
    __syncthreads();
  }

#pragma unroll
  for (int mt = 0; mt < 4; ++mt)
#pragma unroll
    for (int nt = 0; nt < NT; ++nt) {
      int col = bn + wn + nt * 16 + l16;
      bool left = col < Nhalf;                 // uniform: 64-col strips
      int cc = left ? col : col - Nhalf;
      float b = left ? bl[cc] : br[cc];
      unsigned short* Cp = left ? Cl : Cr;
#pragma unroll
      for (int r = 0; r < 4; ++r) {
        int row = bm + wm + mt * 16 + lq * 4 + r;
        if (row < M) Cp[(size_t)row * Nhalf + cc] = f2b(acc[mt][nt][r] + b);
      }
    }
}

// ---------------------------------------------------------------- fused GATv2 aggregate
// R4 structure (best anchor: 289.4 us): ONE wave per destination node, 4 nodes
// per 256-thread block, per-chunk se broadcast load (compiler prefetches it —
// R7's readlane rewrite put it ON the chain and regressed; reverted).
// Packed f32x2 VOP3P math; wgt-mask only in tail chunk.
// R8: EPC (edges per chunk) template param. gat1 keeps 4 (VGPR-capped).
// gat2 uses 8: it runs the SAME chunk count as gat1 (same degrees) with 8x
// less data -> latency-chain-bound; halving chain count should halve its time.
// Keep VGPR <= 64 (R1: >64 halves wave cap; R5: min-waves clamp caused spills).
template <int D, int EPC, bool DO_SILU, bool OBF, bool HEAD_GEMM>
__global__ __launch_bounds__(256) void k_gat_node(
    const int2* __restrict__ se,
    const int* __restrict__ cnti, const float* __restrict__ lsum,
    const unsigned short* __restrict__ xl, const unsigned short* __restrict__ xr,
    const float* __restrict__ We, const float* __restrict__ att,
    const float* __restrict__ bias, const float* __restrict__ w_ln,
    const float* __restrict__ Wout,
    unsigned short* __restrict__ outb, float* __restrict__ outf) {
  constexpr int VEC = D / 64;      // channels per lane (8 for D1, 2 for D2)
  constexpr int PAIRS = VEC / 2;   // f32x2 pairs per lane
  const int w = __builtin_amdgcn_readfirstlane(threadIdx.x) >> 6;  // SGPR wave id
  const int n = blockIdx.x * 4 + w;                                // SGPR node
  const int lane = threadIdx.x & 63;
  const int c0 = lane * VEC;

  f32x2 xd2[PAIRS], we2[PAIRS], at2[PAIRS], acc2[PAIRS];
  {
    unsigned int tr[PAIRS];
    if constexpr (PAIRS == 4) {
      uint4 t = *(const uint4*)(xr + (size_t)n * D + c0);
      tr[0] = t.x; tr[1] = t.y; tr[2] = t.z; tr[3] = t.w;
    } else {
      tr[0] = *(const unsigned int*)(xr + (size_t)n * D + c0);
    }
    const f32x2* Wep = (const f32x2*)(We + c0);
    const f32x2* atp = (const f32x2*)(att + c0);
#pragma unroll
    for (int i = 0; i < PAIRS; i++) {
      xd2[i] = bpair(tr[i]);
      we2[i] = Wep[i];
      at2[i] = atp[i];
      acc2[i] = (f32x2){0.f, 0.f};
    }
  }

  const int start = n * CAP;
  const int deg = cnti[n];
  const int total = deg + 1;                    // + self-loop
  const float lan = lsum[n] / fmaxf((float)deg, 1.0f);
  float denom = 0.f;
  const int nfull = total / EPC;                // wave-uniform
  const int rem = total % EPC;

  // one EPC-edge chunk; mask is a compile-time-constant bool at both call sites
  auto chunk = [&](int base, bool mask) {
    int s[EPC]; float eav[EPC], wgt[EPC];
#pragma unroll
    for (int k = 0; k < EPC; k++) {
      int idx = base + k;
      if (idx < deg) { int2 e = se[start + idx]; s[k] = e.x; eav[k] = __int_as_float(e.y); }
      else           { s[k] = n; eav[k] = lan; }
      if (mask) wgt[k] = (idx < total) ? 1.f : 0.f;
    }
    unsigned int uu[EPC][PAIRS];
#pragma unroll
    for (int k = 0; k < EPC; k++) {                // EPC gathers in flight
      if constexpr (PAIRS == 4) {
        uint4 t = *(const uint4*)(xl + (size_t)s[k] * D + c0);
        uu[k][0] = t.x; uu[k][1] = t.y; uu[k][2] = t.z; uu[k][3] = t.w;
      } else {
        uu[k][0] = *(const unsigned int*)(xl + (size_t)s[k] * D + c0);
      }
    }
    f32x2 xs2[EPC][PAIRS];
    f32x2 p2[EPC];
#pragma unroll
    for (int j = 0; j < EPC; j++) p2[j] = (f32x2){0.f, 0.f};
#pragma unroll
    for (int i = 0; i < PAIRS; i++) {
#pragma unroll
      for (int j = 0; j < EPC; j++) {
        f32x2 xs = bpair(uu[j][i]);
        xs2[j][i] = xs;
        f32x2 ea = {eav[j], eav[j]};
        f32x2 q = __builtin_elementwise_fma(ea, we2[i], xd2[i]) + xs;  // pk_fma + pk_add
        f32x2 ql = __builtin_elementwise_max(q, q * 0.2f);             // pk_mul + 2*max
        p2[j] = __builtin_elementwise_fma(at2[i], ql, p2[j]);          // pk_fma
      }
    }
    float p[EPC];
#pragma unroll
    for (int j = 0; j < EPC; j++) p[j] = p2[j].x + p2[j].y;
#pragma unroll
    for (int o = 16; o > 0; o >>= 1) {           // half-wave butterfly, EPC chains
#pragma unroll
      for (int j = 0; j < EPC; j++) p[j] += __shfl_xor(p[j], o);
    }
    float pe[EPC];
#pragma unroll
    for (int j = 0; j < EPC; j++) {
      pe[j] = __expf(p[j]);
      if (mask) pe[j] *= wgt[j];
      denom += pe[j];
    }
#pragma unroll
    for (int i = 0; i < PAIRS; i++) {
#pragma unroll
      for (int j = 0; j < EPC; j++) {
        f32x2 pv = {pe[j], pe[j]};
        acc2[i] = __builtin_elementwise_fma(pv, xs2[j][i], acc2[i]);   // pk_fma
      }
    }
  };

  for (int it = 0; it < nfull; ++it) chunk(it * EPC, false);
  if (rem) chunk(nfull * EPC, true);

  float inv = 1.f / denom;                       // per-head (per half-wave)
  float vv[VEC], ss = 0.f;
#pragma unroll
  for (int i = 0; i < PAIRS; i++) {
#pragma unroll
    for (int h = 0; h < 2; h++) {
      int k = i * 2 + h;
      float v = fmaf(acc2[i][h], inv, bias[c0 + k]);
      if (DO_SILU) v = v / (1.f + __expf(-v));
      vv[k] = v;
      ss += v * v;
    }
  }
#pragma unroll
  for (int o = 32; o > 0; o >>= 1) ss += __shfl_xor(ss, o);   // full-wave
  float rinv = rsqrtf(ss / (float)D + 1e-5f);

  __shared__ __align__(16) float hrow[4][D2];
#pragma unroll
  for (int k = 0; k < VEC; k++) {
    float o = vv[k] * rinv * w_ln[c0 + k];
    if (OBF) outb[(size_t)n * D + c0 + k] = f2b(o);
    if (HEAD_GEMM) hrow[w][c0 + k] = o;
  }
  if (HEAD_GEMM) {
    __syncthreads();                             // no early returns: NN % 4 == 0
    int t = threadIdx.x;
    if (t < 4 * NCLS) {
      int n4 = t / NCLS, c = t % NCLS;
      const float4* wr = (const float4*)(Wout + c * D2);
      const float4* hr = (const float4*)&hrow[n4][0];
      float sm = 0.f;
#pragma unroll
      for (int q = 0; q < D2 / 4; q++) {
        float4 a = hr[q], b = wr[q];
        sm += a.x * b.x + a.y * b.y + a.z * b.z + a.w * b.w;
      }
      outf[(size_t)(blockIdx.x * 4 + n4) * NCLS + c] = sm;
    }
  }
}

// ---------------------------------------------------------------- launch
extern "C" void kernel_launch(void* const* d_in, const int* in_sizes, int n_in,
                              void* d_out, int out_size, void* d_ws, size_t ws_size,
                              hipStream_t stream) {
  const float* x     = (const float*)d_in[0];
  const int*   ei    = (const int*)  d_in[1];
  const float* eattr = (const float*)d_in[2];
  const float* Wl1   = (const float*)d_in[3];
  const float* bl1   = (const float*)d_in[4];
  const float* Wr1   = (const float*)d_in[5];
  const float* br1   = (const float*)d_in[6];
  const float* We1   = (const float*)d_in[7];
  const float* att1  = (const float*)d_in[8];
  const float* bias1 = (const float*)d_in[9];
  const float* Wl2   = (const float*)d_in[10];
  const float* bl2   = (const float*)d_in[11];
  const float* Wr2   = (const float*)d_in[12];
  const float* br2   = (const float*)d_in[13];
  const float* We2   = (const float*)d_in[14];
  const float* att2  = (const float*)d_in[15];
  const float* bias2 = (const float*)d_in[16];
  const float* w_ln1 = (const float*)d_in[17];
  const float* w_ln3 = (const float*)d_in[18];
  const float* W_out = (const float*)d_in[19];
  float* out = (float*)d_out;
  (void)in_sizes; (void)n_in; (void)out_size; (void)ws_size;

  const int* src = ei;
  const int* dst = ei + NE;

  char* wsp = (char*)d_ws;
  auto alloc = [&](size_t nbytes) {
    char* ptr = wsp;
    wsp += ((nbytes + 255) / 256) * 256;
    return ptr;
  };
  int*   cnti   = (int*)  alloc((size_t)NN * 4);   // } contiguous (NNP ints each),
  float* lsum   = (float*)alloc((size_t)NN * 4);   // } zeroed via one hipMemsetAsync
  int2*  se     = (int2*) alloc((size_t)NN * CAP * 8);   // padded CSR (15.4 MB)
  unsigned short* xb   = (unsigned short*)alloc((size_t)NN * D2 * 2);
  unsigned short* Wc1  = (unsigned short*)alloc((size_t)2 * D1 * D2 * 2);
  unsigned short* Wc2  = (unsigned short*)alloc((size_t)2 * D2 * D1 * 2);
  unsigned short* xl1  = (unsigned short*)alloc((size_t)NN * D1 * 2);  // gather table
  unsigned short* xr1  = (unsigned short*)alloc((size_t)NN * D1 * 2);
  unsigned short* h1b  = (unsigned short*)alloc((size_t)NN * D1 * 2);
  unsigned short* xl2  = (unsigned short*)alloc((size_t)NN * D2 * 2);
  unsigned short* xr2  = (unsigned short*)alloc((size_t)NN * D2 * 2);

  // --- preamble: memset + fused cast/CSR-build ---
  hipMemsetAsync(cnti, 0, (size_t)2 * NNP * 4, stream);
  k_build<<<(IDG_TOT + 255) / 256, 256, 0, stream>>>(
      x, Wl1, Wr1, Wl2, Wr2, src, dst, eattr, cnti, lsum, se, xb, Wc1, Wc2);

  const int GB = NN / 4;             // 4 nodes/block, 1 wave each (NN % 4 == 0)
  const int MB = (NN + 127) / 128;   // 235 row-tiles

  // --- layer 1: [xl1|xr1] = x @ [Wl1;Wr1]^T + [bl1;br1]  (split bf16 out) ---
  gemm_mfma<128, 4, 64><<<dim3(2 * D1 / 128, MB), 256, 0, stream>>>(
      xb, Wc1, bl1, br1, D1, xl1, xr1, NN, 2 * D1, D2);
  k_gat_node<D1, 4, true, true, false><<<GB, 256, 0, stream>>>(
      se, cnti, lsum, xl1, xr1, We1, att1, bias1, w_ln1, nullptr, h1b, nullptr);

  // --- layer 2: [xl2|xr2] = h1 @ [Wl2;Wr2]^T + [bl2;br2]  (split bf16 out) ---
  gemm_mfma<128, 4, 64><<<dim3(2 * D2 / 128, MB), 256, 0, stream>>>(
      h1b, Wc2, bl2, br2, D2, xl2, xr2, NN, 2 * D2, D1);
  k_gat_node<D2, 8, false, false, true><<<GB, 256, 0, stream>>>(
      se, cnti, lsum, xl2, xr2, We2, att2, bias2, w_ln3, W_out, nullptr, out);
}

// Round 9
// 258.390 us; speedup vs baseline: 1.8483x; 1.1128x over previous
//
#include <hip/hip_runtime.h>
#include <cstddef>

#define NN   30000
#define NNP  30016          /* NN ints rounded to 256B alloc granularity */
#define NE   240000
#define D1   512
#define D2   128
#define NCLS 20
#define CAP  64             /* padded-CSR slots per node; Poisson(8) tail @64 ~ 1e-38 */
#define CAST_TOT 1025536          /* x(960000) + 4 weights(16384 ea), float4 units */
#define IDG_TOT  (CAST_TOT + NE)  /* + one thread per edge for CSR-build atomics */

typedef __attribute__((ext_vector_type(8))) short short8;
typedef __attribute__((ext_vector_type(4))) float f32x4;
typedef __attribute__((ext_vector_type(2))) float f32x2;

__device__ __forceinline__ unsigned short f2b(float f) {
  union { float f; unsigned int u; } c; c.f = f;
  unsigned int r = (c.u + 0x7fff + ((c.u >> 16) & 1)) >> 16;  // RNE
  return (unsigned short)r;
}
__device__ __forceinline__ float b2f(unsigned short u) {
  union { unsigned int u; float f; } c; c.u = (unsigned int)u << 16;
  return c.f;
}
// two packed bf16 (little-endian: low half = even channel) -> f32x2
__device__ __forceinline__ f32x2 bpair(unsigned int t) {
  f32x2 r;
  r.x = __uint_as_float(t << 16);
  r.y = __uint_as_float(t & 0xffff0000u);
  return r;
}

// ---------------------------------------------------------------- cast + padded-CSR build
// R9: lsum float-atomics REMOVED (was 240K of k_build's 480K device atomics).
// la (self-loop attr mean) is now computed inside gat from the se entries it
// reads anyway. Only the cnti slot-allocating atomic remains.
__global__ __launch_bounds__(256) void k_build(
    const float* __restrict__ x,
    const float* __restrict__ Wl1, const float* __restrict__ Wr1,
    const float* __restrict__ Wl2, const float* __restrict__ Wr2,
    const int* __restrict__ src, const int* __restrict__ dst,
    const float* __restrict__ eattr,
    int* __restrict__ cnti,
    int2* __restrict__ se,
    unsigned short* __restrict__ xb,
    unsigned short* __restrict__ Wc1, unsigned short* __restrict__ Wc2) {
  int i = blockIdx.x * 256 + threadIdx.x;
  if (i >= IDG_TOT) return;
  if (i >= CAST_TOT) {                 // CSR build atomics
    int e = i - CAST_TOT;
    int d = dst[e];
    int pos = atomicAdd(&cnti[d], 1);
    if (pos < CAP) se[(size_t)d * CAP + pos] = make_int2(src[e], __float_as_int(eattr[e]));
    return;
  }
  const float* in; unsigned short* outp; int off;
  if      (i <  960000) { in = x;   outp = xb;          off = i; }
  else if (i <  976384) { in = Wl1; outp = Wc1;         off = i -  960000; }
  else if (i <  992768) { in = Wr1; outp = Wc1 + 65536; off = i -  976384; }
  else if (i < 1009152) { in = Wl2; outp = Wc2;         off = i -  992768; }
  else                  { in = Wr2; outp = Wc2 + 65536; off = i - 1009152; }
  float4 v = ((const float4*)in)[off];
  ushort4 o;
  o.x = f2b(v.x); o.y = f2b(v.y); o.z = f2b(v.z); o.w = f2b(v.w);
  ((ushort4*)outp)[off] = o;
}

// ---------------------------------------------------------------- bf16 MFMA GEMM
// [Cl|Cr][m,n] = sum_k A[m,k]*W[n,k] + bias, W = [Wl;Wr] concat in n; split out.
// m97-style staging: UNPADDED LDS, global_load_lds width=16. BK=64 both layers.
// R9 epilogue: LDS-staged vectorized C-write. The old per-element 2B scalar
// store scattered 64 lanes over 4 rows (4x32B transactions/instr); now the
// C-tile is staged in LDS (reusing the As/Bs memory after the K-loop's final
// barrier, padded stride BN+8 to keep 16B alignment + spread banks) and
// streamed out as short8: per wave-store 4 rows x 256B contiguous.
// Requires BN | Nhalf so each block is uniformly left/right (holds: 128|512,
// 128|128). No OOB row guard on loads (reads past M land in later workspace
// buffers); the store masks rows >= M.
template <int BN, int NT, int BK>   // NT = BN/32 n-tiles per wave
__global__ __launch_bounds__(256) void gemm_mfma(
    const unsigned short* __restrict__ A, const unsigned short* __restrict__ W,
    const float* __restrict__ bl, const float* __restrict__ br, int Nhalf,
    unsigned short* __restrict__ Cl, unsigned short* __restrict__ Cr,
    int M, int N, int K) {
  constexpr int BM = 128, LDK = BK;    // unpadded (global_load_lds)
  constexpr int RPI = 512 / BK;        // rows per wave per load issue (8@64)
  constexpr int LPR = BK / 8;          // lanes per row (8@64)
  constexpr int CPAD = BN + 8;         // C-stage stride (16B-aligned rows)
  constexpr int SM_STAGE = BM * LDK + BN * LDK;
  constexpr int SM_C = BM * CPAD;
  constexpr int SMEM = SM_STAGE > SM_C ? SM_STAGE : SM_C;
  __shared__ __align__(16) unsigned short smem[SMEM];
  unsigned short* As = smem;
  unsigned short* Bs = smem + BM * LDK;
  const int bm = blockIdx.y * BM;
  const int bn = blockIdx.x * BN;
  const int tid = threadIdx.x;
  const int lane = tid & 63;
  const int wid = __builtin_amdgcn_readfirstlane(tid >> 6);  // wave-uniform (SGPR)
  const int wm = (wid >> 1) * 64;
  const int wn = (wid & 1) * (NT * 16);
  const int l16 = lane & 15, lq = lane >> 4;
  const int lrow = lane / LPR;         // staging: row within RPI
  const int lcol = (lane % LPR) * 8;   // staging: k-offset (8 bf16 = 16 B)

  f32x4 acc[4][NT];
#pragma unroll
  for (int i = 0; i < 4; ++i)
#pragma unroll
    for (int j = 0; j < NT; ++j) acc[i][j] = (f32x4){0.f, 0.f, 0.f, 0.f};

  for (int k0 = 0; k0 < K; k0 += BK) {
#pragma unroll
    for (int p = 0; p < BM / (4 * RPI); ++p) {
      int r = p * (4 * RPI) + wid * RPI;
      const unsigned short* gp = A + (size_t)(bm + r + lrow) * K + k0 + lcol;
      __builtin_amdgcn_global_load_lds(
          (const __attribute__((address_space(1))) unsigned int*)gp,
          (__attribute__((address_space(3))) unsigned int*)(As + (size_t)r * LDK),
          16, 0, 0);
    }
#pragma unroll
    for (int p = 0; p < BN / (4 * RPI); ++p) {
      int r = p * (4 * RPI) + wid * RPI;
      const unsigned short* gp = W + (size_t)(bn + r + lrow) * K + k0 + lcol;
      __builtin_amdgcn_global_load_lds(
          (const __attribute__((address_space(1))) unsigned int*)gp,
          (__attribute__((address_space(3))) unsigned int*)(Bs + (size_t)r * LDK),
          16, 0, 0);
    }
    __syncthreads();
#pragma unroll
    for (int kh = 0; kh < BK / 32; ++kh) {
      short8 af[4], bfr[NT];
#pragma unroll
      for (int mt = 0; mt < 4; ++mt)
        af[mt] = *(const short8*)&As[(wm + mt * 16 + l16) * LDK + kh * 32 + lq * 8];
#pragma unroll
      for (int nt = 0; nt < NT; ++nt)
        bfr[nt] = *(const short8*)&Bs[(wn + nt * 16 + l16) * LDK + kh * 32 + lq * 8];
#pragma unroll
      for (int mt = 0; mt < 4; ++mt)
#pragma unroll
        for (int nt = 0; nt < NT; ++nt)
          acc[mt][nt] = __builtin_amdgcn_mfma_f32_16x16x32_bf16(
              af[mt], bfr[nt], acc[mt][nt], 0, 0, 0);
    }
    __syncthreads();
  }
  // K-loop ended with a barrier: safe to reuse smem as the C-stage.
  unsigned short* Cs = smem;           // [BM][CPAD]
  const bool left = bn < Nhalf;        // block-uniform (BN | Nhalf)
  const int ccb = left ? bn : bn - Nhalf;
  const float* bptr = left ? bl : br;
  unsigned short* Cp = left ? Cl : Cr;

#pragma unroll
  for (int nt = 0; nt < NT; ++nt) {
    int lc = wn + nt * 16 + l16;
    float b = bptr[ccb + lc];
#pragma unroll
    for (int mt = 0; mt < 4; ++mt)
#pragma unroll
      for (int r = 0; r < 4; ++r)
        Cs[(wm + mt * 16 + lq * 4 + r) * CPAD + lc] = f2b(acc[mt][nt][r] + b);
  }
  __syncthreads();
  constexpr int CHR = BN / 8;                  // 16B chunks per row
  constexpr int NPASS = BM * CHR / 256;        // chunks per thread
#pragma unroll
  for (int p = 0; p < NPASS; ++p) {
    int c = p * 256 + tid;
    int row = c / CHR, col8 = (c % CHR) * 8;
    if (bm + row < M)
      *(short8*)&Cp[(size_t)(bm + row) * Nhalf + ccb + col8] =
          *(const short8*)&Cs[row * CPAD + col8];
  }
}

// ---------------------------------------------------------------- fused GATv2 aggregate
// R4 structure (anchor): ONE wave per destination node, 4 nodes per 256-thread
// block, per-chunk se broadcast load (compiler prefetches it; R7's readlane
// rewrite regressed). Packed f32x2 VOP3P math. EPC=4 (gat1) / 8 (gat2).
// R9: la computed in-kernel. Full chunks cover EDGES only and accumulate
// easum (wave-uniform adds, free); the tail chunk (always present: deg%EPC
// edges + self-loop) finishes easum, forms lan = easum/deg, and processes the
// self-loop + inert slots under the wgt mask. Same per-edge order as before.
// Keep VGPR <= 64 (R1: >64 halves wave cap; R5: min-waves clamp caused spills).
template <int D, int EPC, bool DO_SILU, bool OBF, bool HEAD_GEMM>
__global__ __launch_bounds__(256) void k_gat_node(
    const int2* __restrict__ se,
    const int* __restrict__ cnti,
    const unsigned short* __restrict__ xl, const unsigned short* __restrict__ xr,
    const float* __restrict__ We, const float* __restrict__ att,
    const float* __restrict__ bias, const float* __restrict__ w_ln,
    const float* __restrict__ Wout,
    unsigned short* __restrict__ outb, float* __restrict__ outf) {
  constexpr int VEC = D / 64;      // channels per lane (8 for D1, 2 for D2)
  constexpr int PAIRS = VEC / 2;   // f32x2 pairs per lane
  const int w = __builtin_amdgcn_readfirstlane(threadIdx.x) >> 6;  // SGPR wave id
  const int n = blockIdx.x * 4 + w;                                // SGPR node
  const int lane = threadIdx.x & 63;
  const int c0 = lane * VEC;

  f32x2 xd2[PAIRS], we2[PAIRS], at2[PAIRS], acc2[PAIRS];
  {
    unsigned int tr[PAIRS];
    if constexpr (PAIRS == 4) {
      uint4 t = *(const uint4*)(xr + (size_t)n * D + c0);
      tr[0] = t.x; tr[1] = t.y; tr[2] = t.z; tr[3] = t.w;
    } else {
      tr[0] = *(const unsigned int*)(xr + (size_t)n * D + c0);
    }
    const f32x2* Wep = (const f32x2*)(We + c0);
    const f32x2* atp = (const f32x2*)(att + c0);
#pragma unroll
    for (int i = 0; i < PAIRS; i++) {
      xd2[i] = bpair(tr[i]);
      we2[i] = Wep[i];
      at2[i] = atp[i];
      acc2[i] = (f32x2){0.f, 0.f};
    }
  }

  const int start = n * CAP;
  const int deg = cnti[n];
  float denom = 0.f;
  float easum = 0.f;
  const int nfullE = deg / EPC;                 // full chunks of EDGES only

  // shared chunk body; wgt==nullptr folds the mask away at the full-chunk site
  auto body = [&](const int (&s)[EPC], const float (&eav)[EPC], const float* wgt) {
    unsigned int uu[EPC][PAIRS];
#pragma unroll
    for (int k = 0; k < EPC; k++) {                // EPC gathers in flight
      if constexpr (PAIRS == 4) {
        uint4 t = *(const uint4*)(xl + (size_t)s[k] * D + c0);
        uu[k][0] = t.x; uu[k][1] = t.y; uu[k][2] = t.z; uu[k][3] = t.w;
      } else {
        uu[k][0] = *(const unsigned int*)(xl + (size_t)s[k] * D + c0);
      }
    }
    f32x2 xs2[EPC][PAIRS];
    f32x2 p2[EPC];
#pragma unroll
    for (int j = 0; j < EPC; j++) p2[j] = (f32x2){0.f, 0.f};
#pragma unroll
    for (int i = 0; i < PAIRS; i++) {
#pragma unroll
      for (int j = 0; j < EPC; j++) {
        f32x2 xs = bpair(uu[j][i]);
        xs2[j][i] = xs;
        f32x2 ea = {eav[j], eav[j]};
        f32x2 q = __builtin_elementwise_fma(ea, we2[i], xd2[i]) + xs;  // pk_fma + pk_add
        f32x2 ql = __builtin_elementwise_max(q, q * 0.2f);             // pk_mul + 2*max
        p2[j] = __builtin_elementwise_fma(at2[i], ql, p2[j]);          // pk_fma
      }
    }
    float p[EPC];
#pragma unroll
    for (int j = 0; j < EPC; j++) p[j] = p2[j].x + p2[j].y;
#pragma unroll
    for (int o = 16; o > 0; o >>= 1) {           // half-wave butterfly, EPC chains
#pragma unroll
      for (int j = 0; j < EPC; j++) p[j] += __shfl_xor(p[j], o);
    }
    float pe[EPC];
#pragma unroll
    for (int j = 0; j < EPC; j++) {
      pe[j] = __expf(p[j]);
      if (wgt) pe[j] *= wgt[j];
      denom += pe[j];
    }
#pragma unroll
    for (int i = 0; i < PAIRS; i++) {
#pragma unroll
      for (int j = 0; j < EPC; j++) {
        f32x2 pv = {pe[j], pe[j]};
        acc2[i] = __builtin_elementwise_fma(pv, xs2[j][i], acc2[i]);   // pk_fma
      }
    }
  };

  for (int it = 0; it < nfullE; ++it) {          // all slots are edges
    int s[EPC]; float eav[EPC];
#pragma unroll
    for (int k = 0; k < EPC; k++) {
      int2 e = se[start + it * EPC + k];
      s[k] = e.x; eav[k] = __int_as_float(e.y);
      easum += eav[k];
    }
    body(s, eav, nullptr);
  }
  {                                              // tail: edges + self-loop
    const int base = nfullE * EPC;
    int s[EPC]; float eav[EPC]; float wgt[EPC];
#pragma unroll
    for (int k = 0; k < EPC; k++) {
      int idx = base + k;
      if (idx < deg) {
        int2 e = se[start + idx];
        s[k] = e.x; eav[k] = __int_as_float(e.y);
        easum += eav[k];
      }
    }
    float lan = easum / fmaxf((float)deg, 1.0f);
#pragma unroll
    for (int k = 0; k < EPC; k++) {
      int idx = base + k;
      if (idx >= deg) { s[k] = n; eav[k] = lan; }
      wgt[k] = (idx <= deg) ? 1.f : 0.f;         // idx==deg is the self-loop
    }
    body(s, eav, wgt);
  }

  float inv = 1.f / denom;                       // per-head (per half-wave)
  float vv[VEC], ss = 0.f;
#pragma unroll
  for (int i = 0; i < PAIRS; i++) {
#pragma unroll
    for (int h = 0; h < 2; h++) {
      int k = i * 2 + h;
      float v = fmaf(acc2[i][h], inv, bias[c0 + k]);
      if (DO_SILU) v = v / (1.f + __expf(-v));
      vv[k] = v;
      ss += v * v;
    }
  }
#pragma unroll
  for (int o = 32; o > 0; o >>= 1) ss += __shfl_xor(ss, o);   // full-wave
  float rinv = rsqrtf(ss / (float)D + 1e-5f);

  __shared__ __align__(16) float hrow[4][D2];
#pragma unroll
  for (int k = 0; k < VEC; k++) {
    float o = vv[k] * rinv * w_ln[c0 + k];
    if (OBF) outb[(size_t)n * D + c0 + k] = f2b(o);
    if (HEAD_GEMM) hrow[w][c0 + k] = o;
  }
  if (HEAD_GEMM) {
    __syncthreads();                             // no early returns: NN % 4 == 0
    int t = threadIdx.x;
    if (t < 4 * NCLS) {
      int n4 = t / NCLS, c = t % NCLS;
      const float4* wr = (const float4*)(Wout + c * D2);
      const float4* hr = (const float4*)&hrow[n4][0];
      float sm = 0.f;
#pragma unroll
      for (int q = 0; q < D2 / 4; q++) {
        float4 a = hr[q], b = wr[q];
        sm += a.x * b.x + a.y * b.y + a.z * b.z + a.w * b.w;
      }
      outf[(size_t)(blockIdx.x * 4 + n4) * NCLS + c] = sm;
    }
  }
}

// ---------------------------------------------------------------- launch
extern "C" void kernel_launch(void* const* d_in, const int* in_sizes, int n_in,
                              void* d_out, int out_size, void* d_ws, size_t ws_size,
                              hipStream_t stream) {
  const float* x     = (const float*)d_in[0];
  const int*   ei    = (const int*)  d_in[1];
  const float* eattr = (const float*)d_in[2];
  const float* Wl1   = (const float*)d_in[3];
  const float* bl1   = (const float*)d_in[4];
  const float* Wr1   = (const float*)d_in[5];
  const float* br1   = (const float*)d_in[6];
  const float* We1   = (const float*)d_in[7];
  const float* att1  = (const float*)d_in[8];
  const float* bias1 = (const float*)d_in[9];
  const float* Wl2   = (const float*)d_in[10];
  const float* bl2   = (const float*)d_in[11];
  const float* Wr2   = (const float*)d_in[12];
  const float* br2   = (const float*)d_in[13];
  const float* We2   = (const float*)d_in[14];
  const float* att2  = (const float*)d_in[15];
  const float* bias2 = (const float*)d_in[16];
  const float* w_ln1 = (const float*)d_in[17];
  const float* w_ln3 = (const float*)d_in[18];
  const float* W_out = (const float*)d_in[19];
  float* out = (float*)d_out;
  (void)in_sizes; (void)n_in; (void)out_size; (void)ws_size;

  const int* src = ei;
  const int* dst = ei + NE;

  char* wsp = (char*)d_ws;
  auto alloc = [&](size_t nbytes) {
    char* ptr = wsp;
    wsp += ((nbytes + 255) / 256) * 256;
    return ptr;
  };
  int*   cnti   = (int*)  alloc((size_t)NN * 4);   // zeroed via hipMemsetAsync
  int2*  se     = (int2*) alloc((size_t)NN * CAP * 8);   // padded CSR (15.4 MB)
  unsigned short* xb   = (unsigned short*)alloc((size_t)NN * D2 * 2);
  unsigned short* Wc1  = (unsigned short*)alloc((size_t)2 * D1 * D2 * 2);
  unsigned short* Wc2  = (unsigned short*)alloc((size_t)2 * D2 * D1 * 2);
  unsigned short* xl1  = (unsigned short*)alloc((size_t)NN * D1 * 2);  // gather table
  unsigned short* xr1  = (unsigned short*)alloc((size_t)NN * D1 * 2);
  unsigned short* h1b  = (unsigned short*)alloc((size_t)NN * D1 * 2);
  unsigned short* xl2  = (unsigned short*)alloc((size_t)NN * D2 * 2);
  unsigned short* xr2  = (unsigned short*)alloc((size_t)NN * D2 * 2);

  // --- preamble: memset + fused cast/CSR-build ---
  hipMemsetAsync(cnti, 0, (size_t)NNP * 4, stream);
  k_build<<<(IDG_TOT + 255) / 256, 256, 0, stream>>>(
      x, Wl1, Wr1, Wl2, Wr2, src, dst, eattr, cnti, se, xb, Wc1, Wc2);

  const int GB = NN / 4;             // 4 nodes/block, 1 wave each (NN % 4 == 0)
  const int MB = (NN + 127) / 128;   // 235 row-tiles

  // --- layer 1: [xl1|xr1] = x @ [Wl1;Wr1]^T + [bl1;br1]  (split bf16 out) ---
  gemm_mfma<128, 4, 64><<<dim3(2 * D1 / 128, MB), 256, 0, stream>>>(
      xb, Wc1, bl1, br1, D1, xl1, xr1, NN, 2 * D1, D2);
  k_gat_node<D1, 4, true, true, false><<<GB, 256, 0, stream>>>(
      se, cnti, xl1, xr1, We1, att1, bias1, w_ln1, nullptr, h1b, nullptr);

  // --- layer 2: [xl2|xr2] = h1 @ [Wl2;Wr2]^T + [bl2;br2]  (split bf16 out) ---
  gemm_mfma<128, 4, 64><<<dim3(2 * D2 / 128, MB), 256, 0, stream>>>(
      h1b, Wc2, bl2, br2, D2, xl2, xr2, NN, 2 * D2, D1);
  k_gat_node<D2, 8, false, false, true><<<GB, 256, 0, stream>>>(
      se, cnti, xl2, xr2, We2, att2, bias2, w_ln3, W_out, nullptr, out);
}